// Round 1
// baseline (235.229 us; speedup 1.0000x reference)
//
#include <hip/hip_runtime.h>
#include <hip/hip_bf16.h>

typedef unsigned short u16;
typedef __attribute__((ext_vector_type(8))) short short8;
typedef __attribute__((ext_vector_type(4))) float f32x4;

#define N_NODES 4096
#define FIN 512
#define KH 8
#define FO 128
#define DM 1024   // KH*FO

__device__ __forceinline__ u16 f2bf(float x) {
    unsigned u = __float_as_uint(x);
    unsigned r = (u + 0x7FFFu + ((u >> 16) & 1u)) >> 16;
    return (u16)r;
}

// ---------------- Kernel A: h = x @ W^T + b  (fp32, 128x128x8 tiles) ----------------
__global__ __launch_bounds__(256) void gemm_h(const float* __restrict__ x,
                                              const float* __restrict__ W,
                                              const float* __restrict__ bias,
                                              float* __restrict__ h) {
    __shared__ float As[8][128];
    __shared__ float Bs[8][128];
    const int tid = threadIdx.x;
    const int n0 = blockIdx.x * 128;   // cols of h (0..1023)
    const int m0 = blockIdx.y * 128;   // rows of h (0..4095)
    const int ty = tid >> 4, tx = tid & 15;
    const int lrw = tid >> 1, lq = tid & 1;

    const float* ap = &x[(size_t)(m0 + lrw) * FIN + lq * 4];
    const float* bp = &W[(size_t)(n0 + lrw) * FIN + lq * 4];

    float4 av = *(const float4*)ap;
    float4 bv = *(const float4*)bp;

    float acc[8][8];
#pragma unroll
    for (int i = 0; i < 8; ++i)
#pragma unroll
        for (int j = 0; j < 8; ++j) acc[i][j] = 0.f;

    for (int kt = 0; kt < FIN; kt += 8) {
        __syncthreads();
        As[lq * 4 + 0][lrw] = av.x; As[lq * 4 + 1][lrw] = av.y;
        As[lq * 4 + 2][lrw] = av.z; As[lq * 4 + 3][lrw] = av.w;
        Bs[lq * 4 + 0][lrw] = bv.x; Bs[lq * 4 + 1][lrw] = bv.y;
        Bs[lq * 4 + 2][lrw] = bv.z; Bs[lq * 4 + 3][lrw] = bv.w;
        __syncthreads();
        if (kt + 8 < FIN) {
            av = *(const float4*)(ap + kt + 8);
            bv = *(const float4*)(bp + kt + 8);
        }
#pragma unroll
        for (int kk = 0; kk < 8; ++kk) {
            float4 a0 = *(const float4*)&As[kk][ty * 8];
            float4 a1 = *(const float4*)&As[kk][ty * 8 + 4];
            float4 b0 = *(const float4*)&Bs[kk][tx * 8];
            float4 b1 = *(const float4*)&Bs[kk][tx * 8 + 4];
            float a[8] = {a0.x, a0.y, a0.z, a0.w, a1.x, a1.y, a1.z, a1.w};
            float b[8] = {b0.x, b0.y, b0.z, b0.w, b1.x, b1.y, b1.z, b1.w};
#pragma unroll
            for (int i = 0; i < 8; ++i)
#pragma unroll
                for (int j = 0; j < 8; ++j) acc[i][j] += a[i] * b[j];
        }
    }

    float4 bb0 = *(const float4*)&bias[n0 + tx * 8];
    float4 bb1 = *(const float4*)&bias[n0 + tx * 8 + 4];
    float badd[8] = {bb0.x, bb0.y, bb0.z, bb0.w, bb1.x, bb1.y, bb1.z, bb1.w};
#pragma unroll
    for (int i = 0; i < 8; ++i) {
        int row = m0 + ty * 8 + i;
        float4 o0, o1;
        o0.x = acc[i][0] + badd[0]; o0.y = acc[i][1] + badd[1];
        o0.z = acc[i][2] + badd[2]; o0.w = acc[i][3] + badd[3];
        o1.x = acc[i][4] + badd[4]; o1.y = acc[i][5] + badd[5];
        o1.z = acc[i][6] + badd[6]; o1.w = acc[i][7] + badd[7];
        *(float4*)&h[(size_t)row * DM + n0 + tx * 8] = o0;
        *(float4*)&h[(size_t)row * DM + n0 + tx * 8 + 4] = o1;
    }
}

// ---------------- Kernel B: left/right per (k,n), one wave each ----------------
__global__ __launch_bounds__(256) void lr_kernel(const float* __restrict__ h,
                                                 const float* __restrict__ aL,
                                                 const float* __restrict__ aR,
                                                 float* __restrict__ left,
                                                 float* __restrict__ right) {
    int gid = blockIdx.x * 256 + threadIdx.x;
    int wid = gid >> 6, lane = gid & 63;
    int k = wid >> 12, n = wid & 4095;
    int f = lane * 2;
    float2 hv = *(const float2*)&h[(size_t)n * DM + k * FO + f];
    float2 al = *(const float2*)&aL[k * FO + f];
    float2 ar = *(const float2*)&aR[k * FO + f];
    float sL = hv.x * al.x + hv.y * al.y;
    float sR = hv.x * ar.x + hv.y * ar.y;
#pragma unroll
    for (int off = 32; off; off >>= 1) {
        sL += __shfl_down(sL, off);
        sR += __shfl_down(sR, off);
    }
    if (lane == 0) {
        left[k * N_NODES + n] = sL;
        right[k * N_NODES + n] = sR;
    }
}

// ---------------- Kernel T: HbT[k*128+f][n] = bf16(h[n][k*128+f]) ----------------
__global__ __launch_bounds__(256) void transpose_h(const float* __restrict__ h,
                                                   u16* __restrict__ HbT) {
    int b = blockIdx.x;
    int k = b >> 7;
    int ft = (b >> 6) & 1;
    int nt = b & 63;
    int n0 = nt * 64, f0 = ft * 64;
    __shared__ u16 T[64][72];
    int tid = threadIdx.x;
    {
        int r = tid >> 2, cq = tid & 3;
#pragma unroll
        for (int i = 0; i < 4; ++i) {
            int c = cq * 16 + i * 4;
            float4 v = *(const float4*)&h[(size_t)(n0 + r) * DM + k * FO + f0 + c];
            T[r][c + 0] = f2bf(v.x); T[r][c + 1] = f2bf(v.y);
            T[r][c + 2] = f2bf(v.z); T[r][c + 3] = f2bf(v.w);
        }
    }
    __syncthreads();
    {
        int fr = tid >> 2, seg = tid & 3;
        unsigned u[8];
#pragma unroll
        for (int i = 0; i < 8; ++i) {
            unsigned lo = T[seg * 16 + 2 * i][fr];
            unsigned hi = T[seg * 16 + 2 * i + 1][fr];
            u[i] = lo | (hi << 16);
        }
        u16* dst = &HbT[(size_t)(k * FO + f0 + fr) * N_NODES + n0 + seg * 16];
        uint4 u0; u0.x = u[0]; u0.y = u[1]; u0.z = u[2]; u0.w = u[3];
        uint4 u1; u1.x = u[4]; u1.y = u[5]; u1.z = u[6]; u1.w = u[7];
        *(uint4*)dst = u0;
        *(uint4*)(dst + 8) = u1;
    }
}

// ---------------- Kernel D: pack mask (int32 0/1) into bitmask ----------------
__global__ __launch_bounds__(256) void pack_mask(const int* __restrict__ mask,
                                                 unsigned long long* __restrict__ mb) {
    int gid = blockIdx.x * 256 + threadIdx.x;
    int wid = gid >> 6, lane = gid & 63;
    int v = mask[(size_t)wid * 64 + lane];
    unsigned long long bits = __ballot(v != 0);
    if (lane == 0) mb[wid] = bits;
}

// ---------------- Kernel C: flash-style masked softmax + PV aggregation ----------------
// grid (64, 8): blockIdx.x = 64-row block, blockIdx.y = head. 256 thr = 4 waves.
__global__ __launch_bounds__(256) void gat_attn(const u16* __restrict__ HbT,
                                                const float* __restrict__ left,
                                                const float* __restrict__ right,
                                                const unsigned long long* __restrict__ mb,
                                                float* __restrict__ out) {
    const int k = blockIdx.y;
    const int n0 = blockIdx.x * 64;
    const int tid = threadIdx.x;
    const int w = tid >> 6, lane = tid & 63;
    const int fr = lane & 15, kg = lane >> 4;

    __shared__ u16 Ht[128 * 72];   // H_k tile transposed: [f][m], stride 72

    const int n_a = n0 + w * 16 + fr;                // this lane's A-fragment row
    const float lef = left[k * N_NODES + n_a];
    const unsigned long long* mrow = mb + (size_t)n_a * 64;

    f32x4 acc[9];
#pragma unroll
    for (int c = 0; c < 9; ++c) acc[c] = 0.f;

    const short o1 = (fr == 0) ? (short)0x3F80 : (short)0;  // bf16 1.0 in col 0
    const short8 ones = {o1, o1, o1, o1, o1, o1, o1, o1};

    const int sf = tid >> 1, sh = tid & 1;           // staging row / half
    const u16* gsrc = HbT + (size_t)(k * FO + sf) * N_NODES + sh * 32;
    u16* ldst = &Ht[sf * 72 + sh * 32];
    const float* rbase = right + k * N_NODES + kg * 8;

    for (int mt = 0; mt < 64; ++mt) {
        const int m0 = mt * 64;
        __syncthreads();
        {   // stage H_k[f][m0..m0+63] -> LDS (16B per load)
            const uint4* s4 = (const uint4*)(gsrc + m0);
            uint4* d4 = (uint4*)ldst;
            d4[0] = s4[0]; d4[1] = s4[1]; d4[2] = s4[2]; d4[3] = s4[3];
        }
        __syncthreads();

        // P fragments (A-layout: lane holds rows fr, k-elems kg*8+v, +32 for kstep1)
        float4 ra0 = *(const float4*)&rbase[m0];
        float4 ra1 = *(const float4*)&rbase[m0 + 4];
        float4 rb0 = *(const float4*)&rbase[m0 + 32];
        float4 rb1 = *(const float4*)&rbase[m0 + 36];
        unsigned long long bits = mrow[mt];
        float r0[8] = {ra0.x, ra0.y, ra0.z, ra0.w, ra1.x, ra1.y, ra1.z, ra1.w};
        float r1[8] = {rb0.x, rb0.y, rb0.z, rb0.w, rb1.x, rb1.y, rb1.z, rb1.w};
        short8 a0, a1;
#pragma unroll
        for (int v = 0; v < 8; ++v) {
            float e0 = lef + r0[v];
            float l0 = fmaxf(e0, 0.2f * e0);              // leaky_relu
            float p0 = ((bits >> (kg * 8 + v)) & 1ull) ? __expf(l0) : 0.f;
            a0[v] = (short)f2bf(p0);
            float e1 = lef + r1[v];
            float l1 = fmaxf(e1, 0.2f * e1);
            float p1 = ((bits >> (kg * 8 + 32 + v)) & 1ull) ? __expf(l1) : 0.f;
            a1[v] = (short)f2bf(p1);
        }

#pragma unroll
        for (int c = 0; c < 8; ++c) {
            const u16* bp2 = &Ht[(c * 16 + fr) * 72 + kg * 8];
            short8 b0 = *(const short8*)bp2;
            short8 b1 = *(const short8*)(bp2 + 32);
            acc[c] = __builtin_amdgcn_mfma_f32_16x16x32_bf16(a0, b0, acc[c], 0, 0, 0);
            acc[c] = __builtin_amdgcn_mfma_f32_16x16x32_bf16(a1, b1, acc[c], 0, 0, 0);
        }
        acc[8] = __builtin_amdgcn_mfma_f32_16x16x32_bf16(a0, ones, acc[8], 0, 0, 0);
        acc[8] = __builtin_amdgcn_mfma_f32_16x16x32_bf16(a1, ones, acc[8], 0, 0, 0);
    }

    // epilogue: C/D layout col=lane&15, row=(lane>>4)*4+reg
#pragma unroll
    for (int j = 0; j < 4; ++j) {
        float S = __shfl(acc[8][j], (lane & 48));   // col-0 lane of this row group
        float inv = 1.0f / S;
        int n_out = n0 + w * 16 + kg * 4 + j;
        float* orow = out + (size_t)n_out * DM + k * FO + fr;
#pragma unroll
        for (int c = 0; c < 8; ++c) {
            float v = acc[c][j] * inv;
            float e = v > 0.f ? v : (__expf(v) - 1.0f);   // ELU
            orow[c * 16] = e;
        }
    }
}

extern "C" void kernel_launch(void* const* d_in, const int* in_sizes, int n_in,
                              void* d_out, int out_size, void* d_ws, size_t ws_size,
                              hipStream_t stream) {
    const float* x = (const float*)d_in[0];
    const int* mask = (const int*)d_in[1];
    const float* W = (const float*)d_in[2];
    const float* bias = (const float*)d_in[3];
    const float* aL = (const float*)d_in[4];
    const float* aR = (const float*)d_in[5];
    float* out = (float*)d_out;

    char* ws = (char*)d_ws;
    float* h = (float*)ws;                    ws += (size_t)N_NODES * DM * 4;       // 16.78 MB
    u16* HbT = (u16*)ws;                      ws += (size_t)KH * FO * N_NODES * 2;  // 8.39 MB
    float* left = (float*)ws;                 ws += (size_t)KH * N_NODES * 4;       // 128 KB
    float* right = (float*)ws;                ws += (size_t)KH * N_NODES * 4;       // 128 KB
    unsigned long long* mb = (unsigned long long*)ws;                               // 2 MB

    gemm_h<<<dim3(8, 32), dim3(256), 0, stream>>>(x, W, bias, h);
    pack_mask<<<dim3(65536), dim3(256), 0, stream>>>(mask, mb);
    lr_kernel<<<dim3(8192), dim3(256), 0, stream>>>(h, aL, aR, left, right);
    transpose_h<<<dim3(1024), dim3(256), 0, stream>>>(h, HbT);
    gat_attn<<<dim3(64, 8), dim3(256), 0, stream>>>(HbT, left, right, mb, out);
}

// Round 2
// 198.540 us; speedup vs baseline: 1.1848x; 1.1848x over previous
//
#include <hip/hip_runtime.h>
#include <hip/hip_bf16.h>

typedef unsigned short u16;
typedef __attribute__((ext_vector_type(8))) short short8;
typedef __attribute__((ext_vector_type(4))) float f32x4;

#define N_NODES 4096
#define FIN 512
#define KH 8
#define FO 128
#define DM 1024   // KH*FO

__device__ __forceinline__ u16 f2bf(float x) {
    unsigned u = __float_as_uint(x);
    unsigned r = (u + 0x7FFFu + ((u >> 16) & 1u)) >> 16;
    return (u16)r;
}

__device__ __forceinline__ void gload16(const u16* g, u16* l) {
    __builtin_amdgcn_global_load_lds(
        (const __attribute__((address_space(1))) unsigned int*)g,
        (__attribute__((address_space(3))) unsigned int*)l,
        16, 0, 0);
}

// ---------------- Kernel A: h = x @ W^T + b  (fp32, 128x128x8 tiles) ----------------
__global__ __launch_bounds__(256) void gemm_h(const float* __restrict__ x,
                                              const float* __restrict__ W,
                                              const float* __restrict__ bias,
                                              float* __restrict__ h) {
    __shared__ float As[8][128];
    __shared__ float Bs[8][128];
    const int tid = threadIdx.x;
    const int n0 = blockIdx.x * 128;   // cols of h (0..1023)
    const int m0 = blockIdx.y * 128;   // rows of h (0..4095)
    const int ty = tid >> 4, tx = tid & 15;
    const int lrw = tid >> 1, lq = tid & 1;

    const float* ap = &x[(size_t)(m0 + lrw) * FIN + lq * 4];
    const float* bp = &W[(size_t)(n0 + lrw) * FIN + lq * 4];

    float4 av = *(const float4*)ap;
    float4 bv = *(const float4*)bp;

    float acc[8][8];
#pragma unroll
    for (int i = 0; i < 8; ++i)
#pragma unroll
        for (int j = 0; j < 8; ++j) acc[i][j] = 0.f;

    for (int kt = 0; kt < FIN; kt += 8) {
        __syncthreads();
        As[lq * 4 + 0][lrw] = av.x; As[lq * 4 + 1][lrw] = av.y;
        As[lq * 4 + 2][lrw] = av.z; As[lq * 4 + 3][lrw] = av.w;
        Bs[lq * 4 + 0][lrw] = bv.x; Bs[lq * 4 + 1][lrw] = bv.y;
        Bs[lq * 4 + 2][lrw] = bv.z; Bs[lq * 4 + 3][lrw] = bv.w;
        __syncthreads();
        if (kt + 8 < FIN) {
            av = *(const float4*)(ap + kt + 8);
            bv = *(const float4*)(bp + kt + 8);
        }
#pragma unroll
        for (int kk = 0; kk < 8; ++kk) {
            float4 a0 = *(const float4*)&As[kk][ty * 8];
            float4 a1 = *(const float4*)&As[kk][ty * 8 + 4];
            float4 b0 = *(const float4*)&Bs[kk][tx * 8];
            float4 b1 = *(const float4*)&Bs[kk][tx * 8 + 4];
            float a[8] = {a0.x, a0.y, a0.z, a0.w, a1.x, a1.y, a1.z, a1.w};
            float b[8] = {b0.x, b0.y, b0.z, b0.w, b1.x, b1.y, b1.z, b1.w};
#pragma unroll
            for (int i = 0; i < 8; ++i)
#pragma unroll
                for (int j = 0; j < 8; ++j) acc[i][j] += a[i] * b[j];
        }
    }

    float4 bb0 = *(const float4*)&bias[n0 + tx * 8];
    float4 bb1 = *(const float4*)&bias[n0 + tx * 8 + 4];
    float badd[8] = {bb0.x, bb0.y, bb0.z, bb0.w, bb1.x, bb1.y, bb1.z, bb1.w};
#pragma unroll
    for (int i = 0; i < 8; ++i) {
        int row = m0 + ty * 8 + i;
        float4 o0, o1;
        o0.x = acc[i][0] + badd[0]; o0.y = acc[i][1] + badd[1];
        o0.z = acc[i][2] + badd[2]; o0.w = acc[i][3] + badd[3];
        o1.x = acc[i][4] + badd[4]; o1.y = acc[i][5] + badd[5];
        o1.z = acc[i][6] + badd[6]; o1.w = acc[i][7] + badd[7];
        *(float4*)&h[(size_t)row * DM + n0 + tx * 8] = o0;
        *(float4*)&h[(size_t)row * DM + n0 + tx * 8 + 4] = o1;
    }
}

// ---------------- Kernel B: left/right per (k,n), one wave each ----------------
__global__ __launch_bounds__(256) void lr_kernel(const float* __restrict__ h,
                                                 const float* __restrict__ aL,
                                                 const float* __restrict__ aR,
                                                 float* __restrict__ left,
                                                 float* __restrict__ right) {
    int gid = blockIdx.x * 256 + threadIdx.x;
    int wid = gid >> 6, lane = gid & 63;
    int k = wid >> 12, n = wid & 4095;
    int f = lane * 2;
    float2 hv = *(const float2*)&h[(size_t)n * DM + k * FO + f];
    float2 al = *(const float2*)&aL[k * FO + f];
    float2 ar = *(const float2*)&aR[k * FO + f];
    float sL = hv.x * al.x + hv.y * al.y;
    float sR = hv.x * ar.x + hv.y * ar.y;
#pragma unroll
    for (int off = 32; off; off >>= 1) {
        sL += __shfl_down(sL, off);
        sR += __shfl_down(sR, off);
    }
    if (lane == 0) {
        left[k * N_NODES + n] = sL;
        right[k * N_NODES + n] = sR;
    }
}

// ---------------- Kernel T: HbT[k*128+f][n] = bf16(h[n][k*128+f]) ----------------
__global__ __launch_bounds__(256) void transpose_h(const float* __restrict__ h,
                                                   u16* __restrict__ HbT) {
    int b = blockIdx.x;
    int k = b >> 7;
    int ft = (b >> 6) & 1;
    int nt = b & 63;
    int n0 = nt * 64, f0 = ft * 64;
    __shared__ u16 T[64][72];
    int tid = threadIdx.x;
    {
        int r = tid >> 2, cq = tid & 3;
#pragma unroll
        for (int i = 0; i < 4; ++i) {
            int c = cq * 16 + i * 4;
            float4 v = *(const float4*)&h[(size_t)(n0 + r) * DM + k * FO + f0 + c];
            T[r][c + 0] = f2bf(v.x); T[r][c + 1] = f2bf(v.y);
            T[r][c + 2] = f2bf(v.z); T[r][c + 3] = f2bf(v.w);
        }
    }
    __syncthreads();
    {
        int fr = tid >> 2, seg = tid & 3;
        unsigned u[8];
#pragma unroll
        for (int i = 0; i < 8; ++i) {
            unsigned lo = T[seg * 16 + 2 * i][fr];
            unsigned hi = T[seg * 16 + 2 * i + 1][fr];
            u[i] = lo | (hi << 16);
        }
        u16* dst = &HbT[(size_t)(k * FO + f0 + fr) * N_NODES + n0 + seg * 16];
        uint4 u0; u0.x = u[0]; u0.y = u[1]; u0.z = u[2]; u0.w = u[3];
        uint4 u1; u1.x = u[4]; u1.y = u[5]; u1.z = u[6]; u1.w = u[7];
        *(uint4*)dst = u0;
        *(uint4*)(dst + 8) = u1;
    }
}

// ---------------- Kernel D: pack mask (int32 0/1) into bitmask ----------------
__global__ __launch_bounds__(256) void pack_mask(const int* __restrict__ mask,
                                                 unsigned long long* __restrict__ mb) {
    int gid = blockIdx.x * 256 + threadIdx.x;
    int wid = gid >> 6, lane = gid & 63;
    int v = mask[(size_t)wid * 64 + lane];
    unsigned long long bits = __ballot(v != 0);
    if (lane == 0) mb[wid] = bits;
}

// ---------------- Kernel C: flash-style masked softmax + PV aggregation ----------------
// grid (64, 8): blockIdx.x = 64-row block, blockIdx.y = head. 256 thr = 4 waves.
// LDS: double-buffered 128(f) x 64(m) bf16 tile, linear, XOR-swizzled content:
//   logical (f, seg[0..7] of 8 m) lives at element f*64 + (seg ^ (f&7))*8.
// Staged via global_load_lds (linear LDS dest, pre-swizzled per-lane global src).
__global__ __launch_bounds__(256) void gat_attn(const u16* __restrict__ HbT,
                                                const float* __restrict__ left,
                                                const float* __restrict__ right,
                                                const unsigned long long* __restrict__ mb,
                                                float* __restrict__ out) {
    const int k = blockIdx.y;
    const int n0 = blockIdx.x * 64;
    const int tid = threadIdx.x;
    const int w = tid >> 6, lane = tid & 63;
    const int fr = lane & 15, kg = lane >> 4;

    __shared__ u16 Ht[2][128 * 64];   // 2 x 16KB

    const int n_a = n0 + w * 16 + fr;                // this lane's A-fragment row
    const float lef = left[k * N_NODES + n_a];
    const unsigned long long* mrow = mb + (size_t)n_a * 64;

    f32x4 acc[9];
#pragma unroll
    for (int c = 0; c < 9; ++c) acc[c] = 0.f;

    const short o1 = (fr == 0) ? (short)0x3F80 : (short)0;  // bf16 1.0 in col 0
    const short8 ones = {o1, o1, o1, o1, o1, o1, o1, o1};

    // staging: wave w covers f = w*32 + j*8 + (lane>>3), j=0..3; lane fetches
    // the global chunk whose swizzled position is this lane's linear LDS slot.
    const int fsub = lane >> 3;                       // 0..7 within the j-group
    const int seg = ((lane & 7) ^ (fsub & 7)) * 8;    // swizzled m-segment
    const u16* gstage = HbT + (size_t)(k * FO + w * 32 + fsub) * N_NODES + seg;
    u16* lbase = &Ht[0][0] + w * 2048;                // wave's 4KB region (buf 0)

    // read-side swizzled offsets (elements): idx(c,ks) = c*1024 + fr*64 + offks
    const int frx = fr & 7;
    const int off0 = fr * 64 + ((kg) ^ frx) * 8;
    const int off1 = fr * 64 + ((kg + 4) ^ frx) * 8;

    const float* rbase = right + k * N_NODES + kg * 8;

    // prologue: stage tile 0 into buf 0
#pragma unroll
    for (int j = 0; j < 4; ++j)
        gload16(gstage + (size_t)j * 8 * N_NODES, lbase + j * 512);
    __syncthreads();

    int cur = 0;
    for (int mt = 0; mt < 64; ++mt) {
        const int m0 = mt * 64;
        // issue next tile's staging first (overlaps with compute below)
        if (mt < 63) {
            u16* nb = &Ht[cur ^ 1][0] + w * 2048;
            const u16* gs = gstage + (m0 + 64);
#pragma unroll
            for (int j = 0; j < 4; ++j)
                gload16(gs + (size_t)j * 8 * N_NODES, nb + j * 512);
        }

        // P fragments (A-layout: lane holds rows fr, k-elems kg*8+v, +32 for kstep1)
        float4 ra0 = *(const float4*)&rbase[m0];
        float4 ra1 = *(const float4*)&rbase[m0 + 4];
        float4 rb0 = *(const float4*)&rbase[m0 + 32];
        float4 rb1 = *(const float4*)&rbase[m0 + 36];
        unsigned long long bits = mrow[mt];
        float r0[8] = {ra0.x, ra0.y, ra0.z, ra0.w, ra1.x, ra1.y, ra1.z, ra1.w};
        float r1[8] = {rb0.x, rb0.y, rb0.z, rb0.w, rb1.x, rb1.y, rb1.z, rb1.w};
        short8 a0, a1;
#pragma unroll
        for (int v = 0; v < 8; ++v) {
            float e0 = lef + r0[v];
            float l0 = fmaxf(e0, 0.2f * e0);              // leaky_relu
            float p0 = ((bits >> (kg * 8 + v)) & 1ull) ? __expf(l0) : 0.f;
            a0[v] = (short)f2bf(p0);
            float e1 = lef + r1[v];
            float l1 = fmaxf(e1, 0.2f * e1);
            float p1 = ((bits >> (kg * 8 + 32 + v)) & 1ull) ? __expf(l1) : 0.f;
            a1[v] = (short)f2bf(p1);
        }

        const u16* hb = &Ht[cur][0];
#pragma unroll
        for (int c = 0; c < 8; ++c) {
            short8 b0 = *(const short8*)(hb + c * 1024 + off0);
            short8 b1 = *(const short8*)(hb + c * 1024 + off1);
            acc[c] = __builtin_amdgcn_mfma_f32_16x16x32_bf16(a0, b0, acc[c], 0, 0, 0);
            acc[c] = __builtin_amdgcn_mfma_f32_16x16x32_bf16(a1, b1, acc[c], 0, 0, 0);
        }
        acc[8] = __builtin_amdgcn_mfma_f32_16x16x32_bf16(a0, ones, acc[8], 0, 0, 0);
        acc[8] = __builtin_amdgcn_mfma_f32_16x16x32_bf16(a1, ones, acc[8], 0, 0, 0);

        __syncthreads();   // drains next-tile loads (vmcnt0) + guards buffer reuse
        cur ^= 1;
    }

    // epilogue: C/D layout col=lane&15, row=(lane>>4)*4+reg
#pragma unroll
    for (int j = 0; j < 4; ++j) {
        float S = __shfl(acc[8][j], (lane & 48));   // col-0 lane of this row group
        float inv = 1.0f / S;
        int n_out = n0 + w * 16 + kg * 4 + j;
        float* orow = out + (size_t)n_out * DM + k * FO + fr;
#pragma unroll
        for (int c = 0; c < 8; ++c) {
            float v = acc[c][j] * inv;
            float e = v > 0.f ? v : (__expf(v) - 1.0f);   // ELU
            orow[c * 16] = e;
        }
    }
}

extern "C" void kernel_launch(void* const* d_in, const int* in_sizes, int n_in,
                              void* d_out, int out_size, void* d_ws, size_t ws_size,
                              hipStream_t stream) {
    const float* x = (const float*)d_in[0];
    const int* mask = (const int*)d_in[1];
    const float* W = (const float*)d_in[2];
    const float* bias = (const float*)d_in[3];
    const float* aL = (const float*)d_in[4];
    const float* aR = (const float*)d_in[5];
    float* out = (float*)d_out;

    char* ws = (char*)d_ws;
    float* h = (float*)ws;                    ws += (size_t)N_NODES * DM * 4;       // 16.78 MB
    u16* HbT = (u16*)ws;                      ws += (size_t)KH * FO * N_NODES * 2;  // 8.39 MB
    float* left = (float*)ws;                 ws += (size_t)KH * N_NODES * 4;       // 128 KB
    float* right = (float*)ws;                ws += (size_t)KH * N_NODES * 4;       // 128 KB
    unsigned long long* mb = (unsigned long long*)ws;                               // 2 MB

    gemm_h<<<dim3(8, 32), dim3(256), 0, stream>>>(x, W, bias, h);
    pack_mask<<<dim3(65536), dim3(256), 0, stream>>>(mask, mb);
    lr_kernel<<<dim3(8192), dim3(256), 0, stream>>>(h, aL, aR, left, right);
    transpose_h<<<dim3(1024), dim3(256), 0, stream>>>(h, HbT);
    gat_attn<<<dim3(64, 8), dim3(256), 0, stream>>>(HbT, left, right, mb, out);
}

// Round 3
// 185.833 us; speedup vs baseline: 1.2658x; 1.0684x over previous
//
#include <hip/hip_runtime.h>
#include <hip/hip_bf16.h>

typedef unsigned short u16;
typedef __attribute__((ext_vector_type(8))) short short8;
typedef __attribute__((ext_vector_type(4))) float f32x4;

#define N_NODES 4096
#define FIN 512
#define KH 8
#define FO 128
#define DM 1024   // KH*FO
#define LOG2E 1.44269504088896340736f

__device__ __forceinline__ void gload16(const u16* g, u16* l) {
    __builtin_amdgcn_global_load_lds(
        (const __attribute__((address_space(1))) unsigned int*)g,
        (__attribute__((address_space(3))) unsigned int*)l,
        16, 0, 0);
}

__device__ __forceinline__ unsigned pk_bf16(float lo, float hi) {
    unsigned r;
    asm("v_cvt_pk_bf16_f32 %0, %1, %2" : "=v"(r) : "v"(lo), "v"(hi));
    return r;
}

// ---------------- Kernel A: fused h-GEMM + left/right + bf16 transpose ----------------
// grid (8 heads, 32 node-blocks), 256 threads. Never materializes fp32 h.
// Produces: left/right (pre-scaled by log2e), HbT[k*128+f][node] bf16.
__global__ __launch_bounds__(256) void gemm_fused(const float* __restrict__ x,
                                                  const float* __restrict__ W,
                                                  const float* __restrict__ bias,
                                                  const float* __restrict__ aL,
                                                  const float* __restrict__ aR,
                                                  float* __restrict__ left,
                                                  float* __restrict__ right,
                                                  u16* __restrict__ HbT) {
    __shared__ float As[8][128];
    __shared__ float Bs[8][128];
    __shared__ u16 T[128][136];   // bf16 transpose bounce, padded
    const int tid = threadIdx.x;
    const int k = blockIdx.x;            // head
    const int n0 = k * 128;              // DM column base
    const int m0 = blockIdx.y * 128;     // node row base
    const int ty = tid >> 4, tx = tid & 15;
    const int lrw = tid >> 1, lq = tid & 1;

    const float* ap = &x[(size_t)(m0 + lrw) * FIN + lq * 4];
    const float* bp = &W[(size_t)(n0 + lrw) * FIN + lq * 4];

    float4 av = *(const float4*)ap;
    float4 bv = *(const float4*)bp;

    float acc[8][8];
#pragma unroll
    for (int i = 0; i < 8; ++i)
#pragma unroll
        for (int j = 0; j < 8; ++j) acc[i][j] = 0.f;

    for (int kt = 0; kt < FIN; kt += 8) {
        __syncthreads();
        As[lq * 4 + 0][lrw] = av.x; As[lq * 4 + 1][lrw] = av.y;
        As[lq * 4 + 2][lrw] = av.z; As[lq * 4 + 3][lrw] = av.w;
        Bs[lq * 4 + 0][lrw] = bv.x; Bs[lq * 4 + 1][lrw] = bv.y;
        Bs[lq * 4 + 2][lrw] = bv.z; Bs[lq * 4 + 3][lrw] = bv.w;
        __syncthreads();
        if (kt + 8 < FIN) {
            av = *(const float4*)(ap + kt + 8);
            bv = *(const float4*)(bp + kt + 8);
        }
#pragma unroll
        for (int kk = 0; kk < 8; ++kk) {
            float4 a0 = *(const float4*)&As[kk][ty * 8];
            float4 a1 = *(const float4*)&As[kk][ty * 8 + 4];
            float4 b0 = *(const float4*)&Bs[kk][tx * 8];
            float4 b1 = *(const float4*)&Bs[kk][tx * 8 + 4];
            float a[8] = {a0.x, a0.y, a0.z, a0.w, a1.x, a1.y, a1.z, a1.w};
            float b[8] = {b0.x, b0.y, b0.z, b0.w, b1.x, b1.y, b1.z, b1.w};
#pragma unroll
            for (int i = 0; i < 8; ++i)
#pragma unroll
                for (int j = 0; j < 8; ++j) acc[i][j] += a[i] * b[j];
        }
    }

    // bias into acc
    float4 bb0 = *(const float4*)&bias[n0 + tx * 8];
    float4 bb1 = *(const float4*)&bias[n0 + tx * 8 + 4];
    float badd[8] = {bb0.x, bb0.y, bb0.z, bb0.w, bb1.x, bb1.y, bb1.z, bb1.w};
#pragma unroll
    for (int i = 0; i < 8; ++i)
#pragma unroll
        for (int j = 0; j < 8; ++j) acc[i][j] += badd[j];

    // left/right partial dots + 16-lane shuffle reduce (lanes sharing ty)
    float4 al0 = *(const float4*)&aL[k * FO + tx * 8];
    float4 al1 = *(const float4*)&aL[k * FO + tx * 8 + 4];
    float4 ar0 = *(const float4*)&aR[k * FO + tx * 8];
    float4 ar1 = *(const float4*)&aR[k * FO + tx * 8 + 4];
    float alv[8] = {al0.x, al0.y, al0.z, al0.w, al1.x, al1.y, al1.z, al1.w};
    float arv[8] = {ar0.x, ar0.y, ar0.z, ar0.w, ar1.x, ar1.y, ar1.z, ar1.w};
    float sL[8], sR[8];
#pragma unroll
    for (int i = 0; i < 8; ++i) {
        float l = 0.f, r = 0.f;
#pragma unroll
        for (int j = 0; j < 8; ++j) { l += acc[i][j] * alv[j]; r += acc[i][j] * arv[j]; }
        sL[i] = l; sR[i] = r;
    }
#pragma unroll
    for (int off = 1; off < 16; off <<= 1) {
#pragma unroll
        for (int i = 0; i < 8; ++i) {
            sL[i] += __shfl_xor(sL[i], off);
            sR[i] += __shfl_xor(sR[i], off);
        }
    }
    if (tx == 0) {
#pragma unroll
        for (int i = 0; i < 8; ++i) {
            left[k * N_NODES + m0 + ty * 8 + i] = sL[i] * LOG2E;
            right[k * N_NODES + m0 + ty * 8 + i] = sR[i] * LOG2E;
        }
    }

    // bf16 transpose via LDS: T[f][n_local]
#pragma unroll
    for (int j = 0; j < 8; ++j)
#pragma unroll
        for (int i = 0; i < 8; i += 2) {
            unsigned r = pk_bf16(acc[i][j], acc[i + 1][j]);
            *(unsigned*)&T[tx * 8 + j][ty * 8 + i] = r;
        }
    __syncthreads();

    {   // coalesced global store: 128 f-rows x 128 nodes
        int f = tid >> 1, half = tid & 1;
        const uint4* src = (const uint4*)&T[f][half * 64];
        uint4* dst = (uint4*)(HbT + (size_t)(k * FO + f) * N_NODES + m0 + half * 64);
#pragma unroll
        for (int q = 0; q < 8; ++q) dst[q] = src[q];
    }
}

// ---------------- Kernel D: pack mask (int32 0/1) into bitmask ----------------
__global__ __launch_bounds__(256) void pack_mask(const int* __restrict__ mask,
                                                 unsigned long long* __restrict__ mb) {
    int gid = blockIdx.x * 256 + threadIdx.x;
    int wid = gid >> 6, lane = gid & 63;
    int v = mask[(size_t)wid * 64 + lane];
    unsigned long long bits = __ballot(v != 0);
    if (lane == 0) mb[wid] = bits;
}

// ---------------- Kernel C: flash-style masked softmax + PV aggregation ----------------
// grid (64, 8), 512 threads = 8 waves: wg = w&3 -> 16-row n-slice, g = w>>2 -> m-half.
// Each wave accumulates its m-half over 32 tiles; fp32 combine via LDS at the end.
__global__ __launch_bounds__(512) void gat_attn(const u16* __restrict__ HbT,
                                                const float* __restrict__ left,
                                                const float* __restrict__ right,
                                                const unsigned long long* __restrict__ mb,
                                                float* __restrict__ out) {
    const int k = blockIdx.y;
    const int n0 = blockIdx.x * 64;
    const int tid = threadIdx.x;
    const int w = tid >> 6, lane = tid & 63;
    const int g = w >> 2, wg = w & 3;
    const int fr = lane & 15, kg = lane >> 4;

    __shared__ u16 Ht[2][2][128 * 64];   // [m-group][buf][tile] = 64 KB

    const int n_a = n0 + wg * 16 + fr;
    const float lef = left[k * N_NODES + n_a];
    const unsigned long long* mrow = mb + (size_t)n_a * 64 + g * 32;

    f32x4 acc[9];
#pragma unroll
    for (int c = 0; c < 9; ++c) acc[c] = 0.f;

    const short o1 = (fr == 0) ? (short)0x3F80 : (short)0;  // bf16 1.0 in col 0
    const short8 ones = {o1, o1, o1, o1, o1, o1, o1, o1};

    // staging: wave wg covers f = wg*32 + j*8 + fsub; lane fetches the global
    // chunk whose swizzled position is this lane's linear LDS slot.
    const int fsub = lane >> 3;
    const int seg = ((lane & 7) ^ fsub) * 8;
    const u16* gstage = HbT + (size_t)(k * FO + wg * 32 + fsub) * N_NODES + g * 2048 + seg;
    u16* lb0 = &Ht[g][0][wg * 2048];
    u16* lb1 = &Ht[g][1][wg * 2048];

    // read-side swizzled offsets
    const int frx = fr & 7;
    const int off0 = fr * 64 + (kg ^ frx) * 8;
    const int off1 = fr * 64 + ((kg + 4) ^ frx) * 8;

    const float* rbase = right + k * N_NODES + kg * 8 + g * 2048;

    // prologue: stage tile 0 of this group
#pragma unroll
    for (int j = 0; j < 4; ++j)
        gload16(gstage + (size_t)j * 8 * N_NODES, lb0 + j * 512);
    __syncthreads();

    int cur = 0;
    for (int mt = 0; mt < 32; ++mt) {
        const int m0 = mt * 64;
        if (mt < 31) {
            u16* nb = cur ? lb0 : lb1;
            const u16* gs = gstage + m0 + 64;
#pragma unroll
            for (int j = 0; j < 4; ++j)
                gload16(gs + (size_t)j * 8 * N_NODES, nb + j * 512);
        }

        float4 ra0 = *(const float4*)&rbase[m0];
        float4 ra1 = *(const float4*)&rbase[m0 + 4];
        float4 rb0 = *(const float4*)&rbase[m0 + 32];
        float4 rb1 = *(const float4*)&rbase[m0 + 36];
        unsigned long long bits = mrow[mt];
        unsigned mlo = (unsigned)(bits >> (kg * 8)) & 0xffu;
        unsigned mhi = (unsigned)(bits >> (kg * 8 + 32)) & 0xffu;
        float r0[8] = {ra0.x, ra0.y, ra0.z, ra0.w, ra1.x, ra1.y, ra1.z, ra1.w};
        float r1[8] = {rb0.x, rb0.y, rb0.z, rb0.w, rb1.x, rb1.y, rb1.z, rb1.w};
        float p0[8], p1[8];
#pragma unroll
        for (int v = 0; v < 8; ++v) {
            float e0 = lef + r0[v];
            float l0 = fmaxf(e0, 0.2f * e0);
            p0[v] = (mlo & (1u << v)) ? exp2f(l0) : 0.f;
            float e1 = lef + r1[v];
            float l1 = fmaxf(e1, 0.2f * e1);
            p1[v] = (mhi & (1u << v)) ? exp2f(l1) : 0.f;
        }
        union { unsigned u[4]; short8 s; } ua, ub;
#pragma unroll
        for (int vp = 0; vp < 4; ++vp) {
            ua.u[vp] = pk_bf16(p0[2 * vp], p0[2 * vp + 1]);
            ub.u[vp] = pk_bf16(p1[2 * vp], p1[2 * vp + 1]);
        }
        short8 a0 = ua.s, a1 = ub.s;

        const u16* hb = &Ht[g][cur][0];
#pragma unroll
        for (int c = 0; c < 8; ++c) {
            short8 b0 = *(const short8*)(hb + c * 1024 + off0);
            short8 b1 = *(const short8*)(hb + c * 1024 + off1);
            acc[c] = __builtin_amdgcn_mfma_f32_16x16x32_bf16(a0, b0, acc[c], 0, 0, 0);
            acc[c] = __builtin_amdgcn_mfma_f32_16x16x32_bf16(a1, b1, acc[c], 0, 0, 0);
        }
        acc[8] = __builtin_amdgcn_mfma_f32_16x16x32_bf16(a0, ones, acc[8], 0, 0, 0);
        acc[8] = __builtin_amdgcn_mfma_f32_16x16x32_bf16(a1, ones, acc[8], 0, 0, 0);

        __syncthreads();
        cur ^= 1;
    }

    // cross-group fp32 combine via LDS (reuses Ht)
    float* cmb = (float*)&Ht[0][0][0];
    if (g == 1) {
        float* base = cmb + wg * (36 * 64);
#pragma unroll
        for (int c = 0; c < 9; ++c)
#pragma unroll
            for (int j = 0; j < 4; ++j) base[(c * 4 + j) * 64 + lane] = acc[c][j];
    }
    __syncthreads();
    if (g == 0) {
        const float* base = cmb + wg * (36 * 64);
#pragma unroll
        for (int c = 0; c < 9; ++c)
#pragma unroll
            for (int j = 0; j < 4; ++j) acc[c][j] += base[(c * 4 + j) * 64 + lane];

        // epilogue: C/D layout col=lane&15, row=(lane>>4)*4+reg
#pragma unroll
        for (int j = 0; j < 4; ++j) {
            float S = __shfl(acc[8][j], (lane & 48));
            float inv = 1.0f / S;
            int n_out = n0 + wg * 16 + kg * 4 + j;
            float* orow = out + (size_t)n_out * DM + k * FO + fr;
#pragma unroll
            for (int c = 0; c < 8; ++c) {
                float v = acc[c][j] * inv;
                float e = v > 0.f ? v : (__expf(v) - 1.0f);   // ELU
                orow[c * 16] = e;
            }
        }
    }
}

extern "C" void kernel_launch(void* const* d_in, const int* in_sizes, int n_in,
                              void* d_out, int out_size, void* d_ws, size_t ws_size,
                              hipStream_t stream) {
    const float* x = (const float*)d_in[0];
    const int* mask = (const int*)d_in[1];
    const float* W = (const float*)d_in[2];
    const float* bias = (const float*)d_in[3];
    const float* aL = (const float*)d_in[4];
    const float* aR = (const float*)d_in[5];
    float* out = (float*)d_out;

    char* ws = (char*)d_ws;
    u16* HbT = (u16*)ws;                      ws += (size_t)KH * FO * N_NODES * 2;  // 8.39 MB
    float* left = (float*)ws;                 ws += (size_t)KH * N_NODES * 4;       // 128 KB
    float* right = (float*)ws;                ws += (size_t)KH * N_NODES * 4;       // 128 KB
    unsigned long long* mb = (unsigned long long*)ws;                               // 2 MB

    gemm_fused<<<dim3(8, 32), dim3(256), 0, stream>>>(x, W, bias, aL, aR, left, right, HbT);
    pack_mask<<<dim3(65536), dim3(256), 0, stream>>>(mask, mb);
    gat_attn<<<dim3(64, 8), dim3(512), 0, stream>>>(HbT, left, right, mb, out);
}

// Round 4
// 142.622 us; speedup vs baseline: 1.6493x; 1.3030x over previous
//
#include <hip/hip_runtime.h>
#include <hip/hip_bf16.h>

typedef unsigned short u16;
typedef __attribute__((ext_vector_type(8))) short short8;
typedef __attribute__((ext_vector_type(4))) float f32x4;
typedef __attribute__((ext_vector_type(16))) float f32x16;

#define N_NODES 4096
#define FIN 512
#define KH 8
#define FO 128
#define DM 1024   // KH*FO
#define LOG2E 1.44269504088896340736f

__device__ __forceinline__ void gload16(const u16* g, u16* l) {
    __builtin_amdgcn_global_load_lds(
        (const __attribute__((address_space(1))) unsigned int*)g,
        (__attribute__((address_space(3))) unsigned int*)l,
        16, 0, 0);
}

__device__ __forceinline__ unsigned pk_bf16(float lo, float hi) {
    unsigned r;
    asm("v_cvt_pk_bf16_f32 %0, %1, %2" : "=v"(r) : "v"(lo), "v"(hi));
    return r;
}

// ---------------- Kernel P: split fp32 -> (hi, lo) bf16 ----------------
__global__ __launch_bounds__(256) void split_bf16(const float* __restrict__ src,
                                                  u16* __restrict__ hi,
                                                  u16* __restrict__ lo,
                                                  int n4) {
    int idx = blockIdx.x * 256 + threadIdx.x;
    if (idx >= n4) return;
    float4 v = ((const float4*)src)[idx];
    unsigned h01 = pk_bf16(v.x, v.y);
    unsigned h23 = pk_bf16(v.z, v.w);
    float hx = __uint_as_float(h01 << 16);
    float hy = __uint_as_float(h01 & 0xffff0000u);
    float hz = __uint_as_float(h23 << 16);
    float hw = __uint_as_float(h23 & 0xffff0000u);
    unsigned l01 = pk_bf16(v.x - hx, v.y - hy);
    unsigned l23 = pk_bf16(v.z - hz, v.w - hw);
    uint2 hv; hv.x = h01; hv.y = h23;
    uint2 lv; lv.x = l01; lv.y = l23;
    ((uint2*)hi)[idx] = hv;
    ((uint2*)lo)[idx] = lv;
}

// ---------------- Kernel A: MFMA split-bf16 GEMM + bias + left/right + bf16 transpose ----
// grid (8 heads, 32 node-blocks), 512 thr = 8 waves (wr=w>>1 in 0..3: 32 nodes;
// wc=w&1: 64 feats). Tile 128x128, K=512 in BK=32 steps, double-buffered 64KB LDS.
// h = xh*wh + xh*wl + xl*wh (fp32 acc) ~= fp32-exact.
__global__ __launch_bounds__(512) void gemm_mfma(const u16* __restrict__ Xh,
                                                 const u16* __restrict__ Xl,
                                                 const u16* __restrict__ Wh,
                                                 const u16* __restrict__ Wl,
                                                 const float* __restrict__ bias,
                                                 const float* __restrict__ aL,
                                                 const float* __restrict__ aR,
                                                 float* __restrict__ left,
                                                 float* __restrict__ right,
                                                 u16* __restrict__ HbT) {
    const int khead = blockIdx.x;
    const int n0 = blockIdx.y * 128;
    const int tid = threadIdx.x;
    const int w = tid >> 6, lane = tid & 63;
    const int wr = w >> 1, wc = w & 1;
    const int c = lane & 31, half = lane >> 5;

    // 2 x 32KB buffers; within buffer (u16 idx): Xh 0, Xl 4096, Wh 8192, Wl 12288.
    // Row pitch 32 u16 (64B); chunk swizzle c' = c ^ sw(row), sw = (row&3)^((row>>2)&3).
    __shared__ u16 S[2][16384];

    // ---- staging setup: wave pair per array ----
    const int sa = w >> 1;           // array 0..3
    const int shv = w & 1;           // row half (64 rows each)
    const int scl = lane & 3;
    const int ssw = ((lane >> 2) ^ (lane >> 4)) & 3;   // sw(row) for this lane's row
    const int sgc = scl ^ ssw;                          // global chunk to fetch
    const u16* gb; int growbase;
    if (sa == 0)      { gb = Xh; growbase = n0; }
    else if (sa == 1) { gb = Xl; growbase = n0; }
    else if (sa == 2) { gb = Wh; growbase = khead * 128; }
    else              { gb = Wl; growbase = khead * 128; }
    const u16* glb = gb + (size_t)(growbase + shv * 64 + (lane >> 2)) * FIN + sgc * 8;
    const int sldsoff = sa * 4096 + shv * 64 * 32;     // wave-uniform LDS base (u16)

    // ---- read-side setup ----
    const int sw = ((c) ^ (c >> 2)) & 3;
    const int aoff = (wr * 32 + c) * 32;
    const int boff0 = 8192 + (wc * 64 + c) * 32;
    const int boff1 = 8192 + (wc * 64 + 32 + c) * 32;

    f32x16 acc0, acc1;
#pragma unroll
    for (int i = 0; i < 16; ++i) { acc0[i] = 0.f; acc1[i] = 0.f; }

    // prologue: stage kt=0 into buf 0
#pragma unroll
    for (int i = 0; i < 4; ++i)
        gload16(glb + (size_t)i * 16 * FIN, &S[0][sldsoff + i * 512]);
    __syncthreads();

    int cur = 0;
    for (int kt = 0; kt < 16; ++kt) {
        if (kt < 15) {
            const u16* gsrc = glb + (kt + 1) * 32;
            u16* dst = &S[cur ^ 1][sldsoff];
#pragma unroll
            for (int i = 0; i < 4; ++i)
                gload16(gsrc + (size_t)i * 16 * FIN, dst + i * 512);
        }

        const u16* sp = S[cur];
        short8 ah[2], al8[2], bh[2][2], bl8[2][2];
#pragma unroll
        for (int ks = 0; ks < 2; ++ks) {
            int ch = ((ks * 2 + half) ^ sw) * 8;
            ah[ks]     = *(const short8*)&sp[aoff + ch];
            al8[ks]    = *(const short8*)&sp[4096 + aoff + ch];
            bh[0][ks]  = *(const short8*)&sp[boff0 + ch];
            bl8[0][ks] = *(const short8*)&sp[boff0 + 4096 + ch];
            bh[1][ks]  = *(const short8*)&sp[boff1 + ch];
            bl8[1][ks] = *(const short8*)&sp[boff1 + 4096 + ch];
        }
#pragma unroll
        for (int ks = 0; ks < 2; ++ks) {
            acc0 = __builtin_amdgcn_mfma_f32_32x32x16_bf16(ah[ks], bh[0][ks], acc0, 0, 0, 0);
            acc0 = __builtin_amdgcn_mfma_f32_32x32x16_bf16(ah[ks], bl8[0][ks], acc0, 0, 0, 0);
            acc0 = __builtin_amdgcn_mfma_f32_32x32x16_bf16(al8[ks], bh[0][ks], acc0, 0, 0, 0);
            acc1 = __builtin_amdgcn_mfma_f32_32x32x16_bf16(ah[ks], bh[1][ks], acc1, 0, 0, 0);
            acc1 = __builtin_amdgcn_mfma_f32_32x32x16_bf16(ah[ks], bl8[1][ks], acc1, 0, 0, 0);
            acc1 = __builtin_amdgcn_mfma_f32_32x32x16_bf16(al8[ks], bh[1][ks], acc1, 0, 0, 0);
        }
        __syncthreads();
        cur ^= 1;
    }

    // ---- epilogue ----
    // C/D layout (32x32): col = lane&31 (feature), row = (reg&3)+8*(reg>>2)+4*half (node)
    const int fglob = khead * FO + wc * 64 + c;       // feature for nf=0; +32 for nf=1
    float b0 = bias[fglob], b1 = bias[fglob + 32];
#pragma unroll
    for (int r = 0; r < 16; ++r) { acc0[r] += b0; acc1[r] += b1; }

    float alv0 = aL[fglob], alv1 = aL[fglob + 32];
    float arv0 = aR[fglob], arv1 = aR[fglob + 32];
    float pl[16], pr[16];
#pragma unroll
    for (int r = 0; r < 16; ++r) {
        pl[r] = acc0[r] * alv0 + acc1[r] * alv1;
        pr[r] = acc0[r] * arv0 + acc1[r] * arv1;
    }
#pragma unroll
    for (int off = 1; off < 32; off <<= 1) {
#pragma unroll
        for (int r = 0; r < 16; ++r) {
            pl[r] += __shfl_xor(pl[r], off);
            pr[r] += __shfl_xor(pr[r], off);
        }
    }

    // T transpose region (u16, pitch 136, 34816B) + LR partials at byte 36864
    u16* T = &S[0][0];
    float* LRf = (float*)&S[0][0] + 9216;   // [wc][2][128] floats

    if (c == 0) {
#pragma unroll
        for (int r = 0; r < 16; ++r) {
            int node = wr * 32 + (r & 3) + 8 * (r >> 2) + 4 * half;
            LRf[(wc * 2 + 0) * 128 + node] = pl[r];
            LRf[(wc * 2 + 1) * 128 + node] = pr[r];
        }
    }

    // T[feat][node] bf16 writes (packed pairs; nodes r&3 are consecutive)
#pragma unroll
    for (int q = 0; q < 4; ++q) {
        int nb = wr * 32 + q * 8 + 4 * half;
        unsigned p00 = pk_bf16(acc0[q * 4 + 0], acc0[q * 4 + 1]);
        unsigned p01 = pk_bf16(acc0[q * 4 + 2], acc0[q * 4 + 3]);
        unsigned p10 = pk_bf16(acc1[q * 4 + 0], acc1[q * 4 + 1]);
        unsigned p11 = pk_bf16(acc1[q * 4 + 2], acc1[q * 4 + 3]);
        *(unsigned*)&T[(wc * 64 + c) * 136 + nb]      = p00;
        *(unsigned*)&T[(wc * 64 + c) * 136 + nb + 2]  = p01;
        *(unsigned*)&T[(wc * 64 + 32 + c) * 136 + nb]     = p10;
        *(unsigned*)&T[(wc * 64 + 32 + c) * 136 + nb + 2] = p11;
    }
    __syncthreads();

    // left/right final combine + store (waves with wc==0)
    if (wc == 0) {
        int node = wr * 32 + (lane & 31);
        if (lane < 32) {
            float L = LRf[0 * 128 + node] + LRf[2 * 128 + node];
            left[khead * N_NODES + n0 + node] = L * LOG2E;
        } else {
            float R = LRf[1 * 128 + node] + LRf[3 * 128 + node];
            right[khead * N_NODES + n0 + node] = R * LOG2E;
        }
    }

    // HbT coalesced store: 512 thr, f = tid>>2, quarter = tid&3 (32 nodes = 64B)
    {
        int f = tid >> 2, q = tid & 3;
        const uint4* src = (const uint4*)&T[f * 136 + q * 32];
        uint4* dst = (uint4*)(HbT + (size_t)(khead * FO + f) * N_NODES + n0 + q * 32);
#pragma unroll
        for (int u = 0; u < 4; ++u) dst[u] = src[u];
    }
}

// ---------------- Kernel D: pack mask (int32 0/1) into bitmask ----------------
__global__ __launch_bounds__(256) void pack_mask(const int* __restrict__ mask,
                                                 unsigned long long* __restrict__ mb) {
    int gid = blockIdx.x * 256 + threadIdx.x;
    int wid = gid >> 6, lane = gid & 63;
    int v = mask[(size_t)wid * 64 + lane];
    unsigned long long bits = __ballot(v != 0);
    if (lane == 0) mb[wid] = bits;
}

// ---------------- Kernel C: flash-style masked softmax + PV aggregation ----------------
// grid (64, 8), 512 threads = 8 waves: wg = w&3 -> 16-row n-slice, g = w>>2 -> m-half.
__global__ __launch_bounds__(512) void gat_attn(const u16* __restrict__ HbT,
                                                const float* __restrict__ left,
                                                const float* __restrict__ right,
                                                const unsigned long long* __restrict__ mb,
                                                float* __restrict__ out) {
    const int k = blockIdx.y;
    const int n0 = blockIdx.x * 64;
    const int tid = threadIdx.x;
    const int w = tid >> 6, lane = tid & 63;
    const int g = w >> 2, wg = w & 3;
    const int fr = lane & 15, kg = lane >> 4;

    __shared__ u16 Ht[2][2][128 * 64];   // [m-group][buf][tile] = 64 KB

    const int n_a = n0 + wg * 16 + fr;
    const float lef = left[k * N_NODES + n_a];
    const unsigned long long* mrow = mb + (size_t)n_a * 64 + g * 32;

    f32x4 acc[9];
#pragma unroll
    for (int c = 0; c < 9; ++c) acc[c] = 0.f;

    const short o1 = (fr == 0) ? (short)0x3F80 : (short)0;
    const short8 ones = {o1, o1, o1, o1, o1, o1, o1, o1};

    const int fsub = lane >> 3;
    const int seg = ((lane & 7) ^ fsub) * 8;
    const u16* gstage = HbT + (size_t)(k * FO + wg * 32 + fsub) * N_NODES + g * 2048 + seg;
    u16* lb0 = &Ht[g][0][wg * 2048];
    u16* lb1 = &Ht[g][1][wg * 2048];

    const int frx = fr & 7;
    const int off0 = fr * 64 + (kg ^ frx) * 8;
    const int off1 = fr * 64 + ((kg + 4) ^ frx) * 8;

    const float* rbase = right + k * N_NODES + kg * 8 + g * 2048;

#pragma unroll
    for (int j = 0; j < 4; ++j)
        gload16(gstage + (size_t)j * 8 * N_NODES, lb0 + j * 512);
    __syncthreads();

    int cur = 0;
    for (int mt = 0; mt < 32; ++mt) {
        const int m0 = mt * 64;
        if (mt < 31) {
            u16* nb = cur ? lb0 : lb1;
            const u16* gs = gstage + m0 + 64;
#pragma unroll
            for (int j = 0; j < 4; ++j)
                gload16(gs + (size_t)j * 8 * N_NODES, nb + j * 512);
        }

        float4 ra0 = *(const float4*)&rbase[m0];
        float4 ra1 = *(const float4*)&rbase[m0 + 4];
        float4 rb0 = *(const float4*)&rbase[m0 + 32];
        float4 rb1 = *(const float4*)&rbase[m0 + 36];
        unsigned long long bits = mrow[mt];
        unsigned mlo = (unsigned)(bits >> (kg * 8)) & 0xffu;
        unsigned mhi = (unsigned)(bits >> (kg * 8 + 32)) & 0xffu;
        float r0[8] = {ra0.x, ra0.y, ra0.z, ra0.w, ra1.x, ra1.y, ra1.z, ra1.w};
        float r1[8] = {rb0.x, rb0.y, rb0.z, rb0.w, rb1.x, rb1.y, rb1.z, rb1.w};
        float p0[8], p1[8];
#pragma unroll
        for (int v = 0; v < 8; ++v) {
            float e0 = lef + r0[v];
            float l0 = fmaxf(e0, 0.2f * e0);
            p0[v] = (mlo & (1u << v)) ? exp2f(l0) : 0.f;
            float e1 = lef + r1[v];
            float l1 = fmaxf(e1, 0.2f * e1);
            p1[v] = (mhi & (1u << v)) ? exp2f(l1) : 0.f;
        }
        union { unsigned u[4]; short8 s; } ua, ub;
#pragma unroll
        for (int vp = 0; vp < 4; ++vp) {
            ua.u[vp] = pk_bf16(p0[2 * vp], p0[2 * vp + 1]);
            ub.u[vp] = pk_bf16(p1[2 * vp], p1[2 * vp + 1]);
        }
        short8 a0 = ua.s, a1 = ub.s;

        const u16* hb = &Ht[g][cur][0];
#pragma unroll
        for (int c = 0; c < 8; ++c) {
            short8 b0 = *(const short8*)(hb + c * 1024 + off0);
            short8 b1 = *(const short8*)(hb + c * 1024 + off1);
            acc[c] = __builtin_amdgcn_mfma_f32_16x16x32_bf16(a0, b0, acc[c], 0, 0, 0);
            acc[c] = __builtin_amdgcn_mfma_f32_16x16x32_bf16(a1, b1, acc[c], 0, 0, 0);
        }
        acc[8] = __builtin_amdgcn_mfma_f32_16x16x32_bf16(a0, ones, acc[8], 0, 0, 0);
        acc[8] = __builtin_amdgcn_mfma_f32_16x16x32_bf16(a1, ones, acc[8], 0, 0, 0);

        __syncthreads();
        cur ^= 1;
    }

    float* cmb = (float*)&Ht[0][0][0];
    if (g == 1) {
        float* base = cmb + wg * (36 * 64);
#pragma unroll
        for (int c = 0; c < 9; ++c)
#pragma unroll
            for (int j = 0; j < 4; ++j) base[(c * 4 + j) * 64 + lane] = acc[c][j];
    }
    __syncthreads();
    if (g == 0) {
        const float* base = cmb + wg * (36 * 64);
#pragma unroll
        for (int c = 0; c < 9; ++c)
#pragma unroll
            for (int j = 0; j < 4; ++j) acc[c][j] += base[(c * 4 + j) * 64 + lane];

#pragma unroll
        for (int j = 0; j < 4; ++j) {
            float S = __shfl(acc[8][j], (lane & 48));
            float inv = 1.0f / S;
            int n_out = n0 + wg * 16 + kg * 4 + j;
            float* orow = out + (size_t)n_out * DM + k * FO + fr;
#pragma unroll
            for (int c = 0; c < 8; ++c) {
                float v = acc[c][j] * inv;
                float e = v > 0.f ? v : (__expf(v) - 1.0f);
                orow[c * 16] = e;
            }
        }
    }
}

extern "C" void kernel_launch(void* const* d_in, const int* in_sizes, int n_in,
                              void* d_out, int out_size, void* d_ws, size_t ws_size,
                              hipStream_t stream) {
    const float* x = (const float*)d_in[0];
    const int* mask = (const int*)d_in[1];
    const float* W = (const float*)d_in[2];
    const float* bias = (const float*)d_in[3];
    const float* aL = (const float*)d_in[4];
    const float* aR = (const float*)d_in[5];
    float* out = (float*)d_out;

    char* ws = (char*)d_ws;
    u16* Xh = (u16*)ws;   ws += (size_t)N_NODES * FIN * 2;   // 4.19 MB
    u16* Xl = (u16*)ws;   ws += (size_t)N_NODES * FIN * 2;   // 4.19 MB
    u16* Wh = (u16*)ws;   ws += (size_t)DM * FIN * 2;        // 1.05 MB
    u16* Wl = (u16*)ws;   ws += (size_t)DM * FIN * 2;        // 1.05 MB
    u16* HbT = (u16*)ws;  ws += (size_t)KH * FO * N_NODES * 2; // 8.39 MB
    float* left = (float*)ws;  ws += (size_t)KH * N_NODES * 4;
    float* right = (float*)ws; ws += (size_t)KH * N_NODES * 4;
    unsigned long long* mb = (unsigned long long*)ws;        // 2 MB

    split_bf16<<<dim3(2048), dim3(256), 0, stream>>>(x, Xh, Xl, N_NODES * FIN / 4);
    split_bf16<<<dim3(512), dim3(256), 0, stream>>>(W, Wh, Wl, DM * FIN / 4);
    gemm_mfma<<<dim3(8, 32), dim3(512), 0, stream>>>(Xh, Xl, Wh, Wl, bias, aL, aR,
                                                     left, right, HbT);
    pack_mask<<<dim3(65536), dim3(256), 0, stream>>>(mask, mb);
    gat_attn<<<dim3(64, 8), dim3(512), 0, stream>>>(HbT, left, right, mb, out);
}

// Round 5
// 134.779 us; speedup vs baseline: 1.7453x; 1.0582x over previous
//
#include <hip/hip_runtime.h>
#include <hip/hip_bf16.h>

typedef unsigned short u16;
typedef __attribute__((ext_vector_type(8))) short short8;
typedef __attribute__((ext_vector_type(2))) float f32x2;
typedef __attribute__((ext_vector_type(4))) float f32x4;
typedef __attribute__((ext_vector_type(16))) float f32x16;

#define N_NODES 4096
#define FIN 512
#define KH 8
#define FO 128
#define DM 1024   // KH*FO
#define LOG2E 1.44269504088896340736f

__device__ __forceinline__ void gload16(const u16* g, u16* l) {
    __builtin_amdgcn_global_load_lds(
        (const __attribute__((address_space(1))) unsigned int*)g,
        (__attribute__((address_space(3))) unsigned int*)l,
        16, 0, 0);
}

__device__ __forceinline__ unsigned pk_bf16(float lo, float hi) {
    unsigned r;
    asm("v_cvt_pk_bf16_f32 %0, %1, %2" : "=v"(r) : "v"(lo), "v"(hi));
    return r;
}

// (c*d, c'*d') in one packed-fp32 mul, then max of the two branches.
__device__ __forceinline__ float pkmul_max(f32x2 a, f32x2 b) {
    f32x2 r;
    asm("v_pk_mul_f32 %0, %1, %2" : "=v"(r) : "v"(a), "v"(b));
    return fmaxf(r.x, r.y);
}

// ---------------- Kernel P: split fp32 -> (hi, lo) bf16 ----------------
__global__ __launch_bounds__(256) void split_bf16(const float* __restrict__ src,
                                                  u16* __restrict__ hi,
                                                  u16* __restrict__ lo,
                                                  int n4) {
    int idx = blockIdx.x * 256 + threadIdx.x;
    if (idx >= n4) return;
    float4 v = ((const float4*)src)[idx];
    unsigned h01 = pk_bf16(v.x, v.y);
    unsigned h23 = pk_bf16(v.z, v.w);
    float hx = __uint_as_float(h01 << 16);
    float hy = __uint_as_float(h01 & 0xffff0000u);
    float hz = __uint_as_float(h23 << 16);
    float hw = __uint_as_float(h23 & 0xffff0000u);
    unsigned l01 = pk_bf16(v.x - hx, v.y - hy);
    unsigned l23 = pk_bf16(v.z - hz, v.w - hw);
    uint2 hv; hv.x = h01; hv.y = h23;
    uint2 lv; lv.x = l01; lv.y = l23;
    ((uint2*)hi)[idx] = hv;
    ((uint2*)lo)[idx] = lv;
}

// ---------------- Kernel A: MFMA split-bf16 GEMM + bias + C/D factor tables + transpose ----
// grid (8 heads, 32 node-blocks), 512 thr = 8 waves. Tile 128x128, BK=32, dbuf 64KB LDS.
// h = xh*wh + xh*wl + xl*wh (fp32 acc) ~= fp32-exact.
// Epilogue emits C2[k][n]=(exp2(L2E*l), exp2(0.2*L2E*l)), D2 likewise for right.
__global__ __launch_bounds__(512) void gemm_mfma(const u16* __restrict__ Xh,
                                                 const u16* __restrict__ Xl,
                                                 const u16* __restrict__ Wh,
                                                 const u16* __restrict__ Wl,
                                                 const float* __restrict__ bias,
                                                 const float* __restrict__ aL,
                                                 const float* __restrict__ aR,
                                                 float2* __restrict__ C2,
                                                 float2* __restrict__ D2,
                                                 u16* __restrict__ HbT) {
    const int khead = blockIdx.x;
    const int n0 = blockIdx.y * 128;
    const int tid = threadIdx.x;
    const int w = tid >> 6, lane = tid & 63;
    const int wr = w >> 1, wc = w & 1;
    const int c = lane & 31, half = lane >> 5;

    __shared__ u16 S[2][16384];

    // ---- staging setup ----
    const int sa = w >> 1;
    const int shv = w & 1;
    const int scl = lane & 3;
    const int ssw = ((lane >> 2) ^ (lane >> 4)) & 3;
    const int sgc = scl ^ ssw;
    const u16* gb; int growbase;
    if (sa == 0)      { gb = Xh; growbase = n0; }
    else if (sa == 1) { gb = Xl; growbase = n0; }
    else if (sa == 2) { gb = Wh; growbase = khead * 128; }
    else              { gb = Wl; growbase = khead * 128; }
    const u16* glb = gb + (size_t)(growbase + shv * 64 + (lane >> 2)) * FIN + sgc * 8;
    const int sldsoff = sa * 4096 + shv * 64 * 32;

    // ---- read-side setup ----
    const int sw = ((c) ^ (c >> 2)) & 3;
    const int aoff = (wr * 32 + c) * 32;
    const int boff0 = 8192 + (wc * 64 + c) * 32;
    const int boff1 = 8192 + (wc * 64 + 32 + c) * 32;

    f32x16 acc0, acc1;
#pragma unroll
    for (int i = 0; i < 16; ++i) { acc0[i] = 0.f; acc1[i] = 0.f; }

#pragma unroll
    for (int i = 0; i < 4; ++i)
        gload16(glb + (size_t)i * 16 * FIN, &S[0][sldsoff + i * 512]);
    __syncthreads();

    int cur = 0;
    for (int kt = 0; kt < 16; ++kt) {
        if (kt < 15) {
            const u16* gsrc = glb + (kt + 1) * 32;
            u16* dst = &S[cur ^ 1][sldsoff];
#pragma unroll
            for (int i = 0; i < 4; ++i)
                gload16(gsrc + (size_t)i * 16 * FIN, dst + i * 512);
        }

        const u16* sp = S[cur];
        short8 ah[2], al8[2], bh[2][2], bl8[2][2];
#pragma unroll
        for (int ks = 0; ks < 2; ++ks) {
            int ch = ((ks * 2 + half) ^ sw) * 8;
            ah[ks]     = *(const short8*)&sp[aoff + ch];
            al8[ks]    = *(const short8*)&sp[4096 + aoff + ch];
            bh[0][ks]  = *(const short8*)&sp[boff0 + ch];
            bl8[0][ks] = *(const short8*)&sp[boff0 + 4096 + ch];
            bh[1][ks]  = *(const short8*)&sp[boff1 + ch];
            bl8[1][ks] = *(const short8*)&sp[boff1 + 4096 + ch];
        }
#pragma unroll
        for (int ks = 0; ks < 2; ++ks) {
            acc0 = __builtin_amdgcn_mfma_f32_32x32x16_bf16(ah[ks], bh[0][ks], acc0, 0, 0, 0);
            acc0 = __builtin_amdgcn_mfma_f32_32x32x16_bf16(ah[ks], bl8[0][ks], acc0, 0, 0, 0);
            acc0 = __builtin_amdgcn_mfma_f32_32x32x16_bf16(al8[ks], bh[0][ks], acc0, 0, 0, 0);
            acc1 = __builtin_amdgcn_mfma_f32_32x32x16_bf16(ah[ks], bh[1][ks], acc1, 0, 0, 0);
            acc1 = __builtin_amdgcn_mfma_f32_32x32x16_bf16(ah[ks], bl8[1][ks], acc1, 0, 0, 0);
            acc1 = __builtin_amdgcn_mfma_f32_32x32x16_bf16(al8[ks], bh[1][ks], acc1, 0, 0, 0);
        }
        __syncthreads();
        cur ^= 1;
    }

    // ---- epilogue ----
    const int fglob = khead * FO + wc * 64 + c;
    float b0 = bias[fglob], b1 = bias[fglob + 32];
#pragma unroll
    for (int r = 0; r < 16; ++r) { acc0[r] += b0; acc1[r] += b1; }

    float alv0 = aL[fglob], alv1 = aL[fglob + 32];
    float arv0 = aR[fglob], arv1 = aR[fglob + 32];
    float pl[16], pr[16];
#pragma unroll
    for (int r = 0; r < 16; ++r) {
        pl[r] = acc0[r] * alv0 + acc1[r] * alv1;
        pr[r] = acc0[r] * arv0 + acc1[r] * arv1;
    }
#pragma unroll
    for (int off = 1; off < 32; off <<= 1) {
#pragma unroll
        for (int r = 0; r < 16; ++r) {
            pl[r] += __shfl_xor(pl[r], off);
            pr[r] += __shfl_xor(pr[r], off);
        }
    }

    u16* T = &S[0][0];
    float* LRf = (float*)&S[0][0] + 9216;

    if (c == 0) {
#pragma unroll
        for (int r = 0; r < 16; ++r) {
            int node = wr * 32 + (r & 3) + 8 * (r >> 2) + 4 * half;
            LRf[(wc * 2 + 0) * 128 + node] = pl[r];
            LRf[(wc * 2 + 1) * 128 + node] = pr[r];
        }
    }

#pragma unroll
    for (int q = 0; q < 4; ++q) {
        int nb = wr * 32 + q * 8 + 4 * half;
        unsigned p00 = pk_bf16(acc0[q * 4 + 0], acc0[q * 4 + 1]);
        unsigned p01 = pk_bf16(acc0[q * 4 + 2], acc0[q * 4 + 3]);
        unsigned p10 = pk_bf16(acc1[q * 4 + 0], acc1[q * 4 + 1]);
        unsigned p11 = pk_bf16(acc1[q * 4 + 2], acc1[q * 4 + 3]);
        *(unsigned*)&T[(wc * 64 + c) * 136 + nb]      = p00;
        *(unsigned*)&T[(wc * 64 + c) * 136 + nb + 2]  = p01;
        *(unsigned*)&T[(wc * 64 + 32 + c) * 136 + nb]     = p10;
        *(unsigned*)&T[(wc * 64 + 32 + c) * 136 + nb + 2] = p11;
    }
    __syncthreads();

    // factor tables: C2 = (exp2(L2E*l), exp2(0.2*L2E*l)); D2 likewise for r
    if (wc == 0) {
        int node = wr * 32 + (lane & 31);
        if (lane < 32) {
            float L = (LRf[0 * 128 + node] + LRf[2 * 128 + node]) * LOG2E;
            float2 cv; cv.x = exp2f(L); cv.y = exp2f(0.2f * L);
            C2[(size_t)khead * N_NODES + n0 + node] = cv;
        } else {
            float R = (LRf[1 * 128 + node] + LRf[3 * 128 + node]) * LOG2E;
            float2 dv; dv.x = exp2f(R); dv.y = exp2f(0.2f * R);
            D2[(size_t)khead * N_NODES + n0 + node] = dv;
        }
    }

    {
        int f = tid >> 2, q = tid & 3;
        const uint4* src = (const uint4*)&T[f * 136 + q * 32];
        uint4* dst = (uint4*)(HbT + (size_t)(khead * FO + f) * N_NODES + n0 + q * 32);
#pragma unroll
        for (int u = 0; u < 4; ++u) dst[u] = src[u];
    }
}

// ---------------- Kernel D: pack mask (int32 0/1) into bitmask ----------------
__global__ __launch_bounds__(256) void pack_mask(const int* __restrict__ mask,
                                                 unsigned long long* __restrict__ mb) {
    int gid = blockIdx.x * 256 + threadIdx.x;
    int wid = gid >> 6, lane = gid & 63;
    int v = mask[(size_t)wid * 64 + lane];
    unsigned long long bits = __ballot(v != 0);
    if (lane == 0) mb[wid] = bits;
}

// ---------------- Kernel C: flash-style masked softmax + PV aggregation ----------------
// grid (64, 8), 512 threads = 8 waves: wg = w&3 -> 16-row n-slice, g = w>>2 -> m-half.
// P[n][m] = mask ? max(c_n*d_m, c'_n*d'_m) : 0   (factored exp, no transcendentals)
__global__ __launch_bounds__(512) void gat_attn(const u16* __restrict__ HbT,
                                                const float2* __restrict__ C2,
                                                const float2* __restrict__ D2,
                                                const unsigned long long* __restrict__ mb,
                                                float* __restrict__ out) {
    const int k = blockIdx.y;
    const int n0 = blockIdx.x * 64;
    const int tid = threadIdx.x;
    const int w = tid >> 6, lane = tid & 63;
    const int g = w >> 2, wg = w & 3;
    const int fr = lane & 15, kg = lane >> 4;

    __shared__ u16 Ht[2][2][128 * 64];   // [m-group][buf][tile] = 64 KB

    const int n_a = n0 + wg * 16 + fr;
    const float2 ccf = C2[(size_t)k * N_NODES + n_a];
    f32x2 cc; cc.x = ccf.x; cc.y = ccf.y;
    const unsigned long long* mrow = mb + (size_t)n_a * 64 + g * 32;

    f32x4 acc[9];
#pragma unroll
    for (int c = 0; c < 9; ++c) acc[c] = 0.f;

    const short o1 = (fr == 0) ? (short)0x3F80 : (short)0;
    const short8 ones = {o1, o1, o1, o1, o1, o1, o1, o1};

    const int fsub = lane >> 3;
    const int seg = ((lane & 7) ^ fsub) * 8;
    const u16* gstage = HbT + (size_t)(k * FO + wg * 32 + fsub) * N_NODES + g * 2048 + seg;
    u16* lb0 = &Ht[g][0][wg * 2048];
    u16* lb1 = &Ht[g][1][wg * 2048];

    const int frx = fr & 7;
    const int off0 = fr * 64 + (kg ^ frx) * 8;
    const int off1 = fr * 64 + ((kg + 4) ^ frx) * 8;

    const float2* D2k = D2 + (size_t)k * N_NODES + g * 2048 + kg * 8;

#pragma unroll
    for (int j = 0; j < 4; ++j)
        gload16(gstage + (size_t)j * 8 * N_NODES, lb0 + j * 512);
    __syncthreads();

    int cur = 0;
    for (int mt = 0; mt < 32; ++mt) {
        const int m0 = mt * 64;
        if (mt < 31) {
            u16* nb = cur ? lb0 : lb1;
            const u16* gs = gstage + m0 + 64;
#pragma unroll
            for (int j = 0; j < 4; ++j)
                gload16(gs + (size_t)j * 8 * N_NODES, nb + j * 512);
        }

        // D factor loads: 8 float2 per 8-entry group (16B-aligned)
        union { float4 f4[4]; f32x2 f2[8]; } Da, Db;
        {
            const float4* dva = (const float4*)(D2k + m0);
            const float4* dvb = (const float4*)(D2k + m0 + 32);
#pragma unroll
            for (int i = 0; i < 4; ++i) { Da.f4[i] = dva[i]; Db.f4[i] = dvb[i]; }
        }
        unsigned long long bits = mrow[mt];
        unsigned m32a = (unsigned)(bits >> (kg * 8));
        unsigned m32b = (unsigned)(bits >> (kg * 8 + 32));

        float p0[8], p1[8];
#pragma unroll
        for (int v = 0; v < 8; ++v) {
            float pa = pkmul_max(cc, Da.f2[v]);
            unsigned sa2 = (unsigned)(((int)(m32a << (31 - v))) >> 31);
            p0[v] = __uint_as_float(__float_as_uint(pa) & sa2);
            float pb = pkmul_max(cc, Db.f2[v]);
            unsigned sb2 = (unsigned)(((int)(m32b << (31 - v))) >> 31);
            p1[v] = __uint_as_float(__float_as_uint(pb) & sb2);
        }
        union { unsigned u[4]; short8 s; } ua, ub;
#pragma unroll
        for (int vp = 0; vp < 4; ++vp) {
            ua.u[vp] = pk_bf16(p0[2 * vp], p0[2 * vp + 1]);
            ub.u[vp] = pk_bf16(p1[2 * vp], p1[2 * vp + 1]);
        }
        short8 a0 = ua.s, a1 = ub.s;

        const u16* hb = &Ht[g][cur][0];
#pragma unroll
        for (int c = 0; c < 8; ++c) {
            short8 b0 = *(const short8*)(hb + c * 1024 + off0);
            short8 b1 = *(const short8*)(hb + c * 1024 + off1);
            acc[c] = __builtin_amdgcn_mfma_f32_16x16x32_bf16(a0, b0, acc[c], 0, 0, 0);
            acc[c] = __builtin_amdgcn_mfma_f32_16x16x32_bf16(a1, b1, acc[c], 0, 0, 0);
        }
        acc[8] = __builtin_amdgcn_mfma_f32_16x16x32_bf16(a0, ones, acc[8], 0, 0, 0);
        acc[8] = __builtin_amdgcn_mfma_f32_16x16x32_bf16(a1, ones, acc[8], 0, 0, 0);

        __syncthreads();
        cur ^= 1;
    }

    float* cmb = (float*)&Ht[0][0][0];
    if (g == 1) {
        float* base = cmb + wg * (36 * 64);
#pragma unroll
        for (int c = 0; c < 9; ++c)
#pragma unroll
            for (int j = 0; j < 4; ++j) base[(c * 4 + j) * 64 + lane] = acc[c][j];
    }
    __syncthreads();
    if (g == 0) {
        const float* base = cmb + wg * (36 * 64);
#pragma unroll
        for (int c = 0; c < 9; ++c)
#pragma unroll
            for (int j = 0; j < 4; ++j) acc[c][j] += base[(c * 4 + j) * 64 + lane];

#pragma unroll
        for (int j = 0; j < 4; ++j) {
            float S = __shfl(acc[8][j], (lane & 48));
            float inv = 1.0f / S;
            int n_out = n0 + wg * 16 + kg * 4 + j;
            float* orow = out + (size_t)n_out * DM + k * FO + fr;
#pragma unroll
            for (int c = 0; c < 8; ++c) {
                float v = acc[c][j] * inv;
                float e = v > 0.f ? v : (__expf(v) - 1.0f);
                orow[c * 16] = e;
            }
        }
    }
}

extern "C" void kernel_launch(void* const* d_in, const int* in_sizes, int n_in,
                              void* d_out, int out_size, void* d_ws, size_t ws_size,
                              hipStream_t stream) {
    const float* x = (const float*)d_in[0];
    const int* mask = (const int*)d_in[1];
    const float* W = (const float*)d_in[2];
    const float* bias = (const float*)d_in[3];
    const float* aL = (const float*)d_in[4];
    const float* aR = (const float*)d_in[5];
    float* out = (float*)d_out;

    char* ws = (char*)d_ws;
    u16* Xh = (u16*)ws;   ws += (size_t)N_NODES * FIN * 2;   // 4.19 MB
    u16* Xl = (u16*)ws;   ws += (size_t)N_NODES * FIN * 2;   // 4.19 MB
    u16* Wh = (u16*)ws;   ws += (size_t)DM * FIN * 2;        // 1.05 MB
    u16* Wl = (u16*)ws;   ws += (size_t)DM * FIN * 2;        // 1.05 MB
    u16* HbT = (u16*)ws;  ws += (size_t)KH * FO * N_NODES * 2; // 8.39 MB
    float2* C2 = (float2*)ws;  ws += (size_t)KH * N_NODES * 8;  // 256 KB
    float2* D2 = (float2*)ws;  ws += (size_t)KH * N_NODES * 8;  // 256 KB
    unsigned long long* mb = (unsigned long long*)ws;        // 2 MB

    split_bf16<<<dim3(2048), dim3(256), 0, stream>>>(x, Xh, Xl, N_NODES * FIN / 4);
    split_bf16<<<dim3(512), dim3(256), 0, stream>>>(W, Wh, Wl, DM * FIN / 4);
    gemm_mfma<<<dim3(8, 32), dim3(512), 0, stream>>>(Xh, Xl, Wh, Wl, bias, aL, aR,
                                                     C2, D2, HbT);
    pack_mask<<<dim3(65536), dim3(256), 0, stream>>>(mask, mb);
    gat_attn<<<dim3(64, 8), dim3(512), 0, stream>>>(HbT, C2, D2, mb, out);
}

// Round 6
// 132.966 us; speedup vs baseline: 1.7691x; 1.0136x over previous
//
#include <hip/hip_runtime.h>
#include <hip/hip_bf16.h>

typedef unsigned short u16;
typedef __attribute__((ext_vector_type(8))) short short8;
typedef __attribute__((ext_vector_type(2))) float f32x2;
typedef __attribute__((ext_vector_type(4))) float f32x4;
typedef __attribute__((ext_vector_type(16))) float f32x16;

#define N_NODES 4096
#define FIN 512
#define KH 8
#define FO 128
#define DM 1024   // KH*FO
#define LOG2E 1.44269504088896340736f

__device__ __forceinline__ void gload16(const u16* g, u16* l) {
    __builtin_amdgcn_global_load_lds(
        (const __attribute__((address_space(1))) unsigned int*)g,
        (__attribute__((address_space(3))) unsigned int*)l,
        16, 0, 0);
}

__device__ __forceinline__ unsigned pk_bf16(float lo, float hi) {
    unsigned r;
    asm("v_cvt_pk_bf16_f32 %0, %1, %2" : "=v"(r) : "v"(lo), "v"(hi));
    return r;
}

// (c*d, c'*d') in one packed-fp32 mul, then max of the two branches.
__device__ __forceinline__ float pkmul_max(f32x2 a, f32x2 b) {
    f32x2 r;
    asm("v_pk_mul_f32 %0, %1, %2" : "=v"(r) : "v"(a), "v"(b));
    return fmaxf(r.x, r.y);
}

// ---------------- Kernel P: split fp32 -> (hi, lo) bf16 ----------------
__global__ __launch_bounds__(256) void split_bf16(const float* __restrict__ src,
                                                  u16* __restrict__ hi,
                                                  u16* __restrict__ lo,
                                                  int n4) {
    int idx = blockIdx.x * 256 + threadIdx.x;
    if (idx >= n4) return;
    float4 v = ((const float4*)src)[idx];
    unsigned h01 = pk_bf16(v.x, v.y);
    unsigned h23 = pk_bf16(v.z, v.w);
    float hx = __uint_as_float(h01 << 16);
    float hy = __uint_as_float(h01 & 0xffff0000u);
    float hz = __uint_as_float(h23 << 16);
    float hw = __uint_as_float(h23 & 0xffff0000u);
    unsigned l01 = pk_bf16(v.x - hx, v.y - hy);
    unsigned l23 = pk_bf16(v.z - hz, v.w - hw);
    uint2 hv; hv.x = h01; hv.y = h23;
    uint2 lv; lv.x = l01; lv.y = l23;
    ((uint2*)hi)[idx] = hv;
    ((uint2*)lo)[idx] = lv;
}

// ---------------- Kernel A: MFMA split-bf16 GEMM + bias + C/D factor tables + transpose ----
// grid (8 heads, 32 node-blocks), 512 thr = 8 waves. Tile 128x128, BK=32, dbuf 64KB LDS.
// h = xh*wh + xh*wl + xl*wh (fp32 acc) ~= fp32-exact.
// Epilogue emits C2[k][n]=(exp2(L2E*l), exp2(0.2*L2E*l)), D2 likewise for right.
__global__ __launch_bounds__(512) void gemm_mfma(const u16* __restrict__ Xh,
                                                 const u16* __restrict__ Xl,
                                                 const u16* __restrict__ Wh,
                                                 const u16* __restrict__ Wl,
                                                 const float* __restrict__ bias,
                                                 const float* __restrict__ aL,
                                                 const float* __restrict__ aR,
                                                 float2* __restrict__ C2,
                                                 float2* __restrict__ D2,
                                                 u16* __restrict__ HbT) {
    const int khead = blockIdx.x;
    const int n0 = blockIdx.y * 128;
    const int tid = threadIdx.x;
    const int w = tid >> 6, lane = tid & 63;
    const int wr = w >> 1, wc = w & 1;
    const int c = lane & 31, half = lane >> 5;

    __shared__ u16 S[2][16384];

    // ---- staging setup ----
    const int sa = w >> 1;
    const int shv = w & 1;
    const int scl = lane & 3;
    const int ssw = ((lane >> 2) ^ (lane >> 4)) & 3;
    const int sgc = scl ^ ssw;
    const u16* gb; int growbase;
    if (sa == 0)      { gb = Xh; growbase = n0; }
    else if (sa == 1) { gb = Xl; growbase = n0; }
    else if (sa == 2) { gb = Wh; growbase = khead * 128; }
    else              { gb = Wl; growbase = khead * 128; }
    const u16* glb = gb + (size_t)(growbase + shv * 64 + (lane >> 2)) * FIN + sgc * 8;
    const int sldsoff = sa * 4096 + shv * 64 * 32;

    // ---- read-side setup ----
    const int sw = ((c) ^ (c >> 2)) & 3;
    const int aoff = (wr * 32 + c) * 32;
    const int boff0 = 8192 + (wc * 64 + c) * 32;
    const int boff1 = 8192 + (wc * 64 + 32 + c) * 32;

    f32x16 acc0, acc1;
#pragma unroll
    for (int i = 0; i < 16; ++i) { acc0[i] = 0.f; acc1[i] = 0.f; }

#pragma unroll
    for (int i = 0; i < 4; ++i)
        gload16(glb + (size_t)i * 16 * FIN, &S[0][sldsoff + i * 512]);
    __syncthreads();

    int cur = 0;
    for (int kt = 0; kt < 16; ++kt) {
        if (kt < 15) {
            const u16* gsrc = glb + (kt + 1) * 32;
            u16* dst = &S[cur ^ 1][sldsoff];
#pragma unroll
            for (int i = 0; i < 4; ++i)
                gload16(gsrc + (size_t)i * 16 * FIN, dst + i * 512);
        }

        const u16* sp = S[cur];
        short8 ah[2], al8[2], bh[2][2], bl8[2][2];
#pragma unroll
        for (int ks = 0; ks < 2; ++ks) {
            int ch = ((ks * 2 + half) ^ sw) * 8;
            ah[ks]     = *(const short8*)&sp[aoff + ch];
            al8[ks]    = *(const short8*)&sp[4096 + aoff + ch];
            bh[0][ks]  = *(const short8*)&sp[boff0 + ch];
            bl8[0][ks] = *(const short8*)&sp[boff0 + 4096 + ch];
            bh[1][ks]  = *(const short8*)&sp[boff1 + ch];
            bl8[1][ks] = *(const short8*)&sp[boff1 + 4096 + ch];
        }
#pragma unroll
        for (int ks = 0; ks < 2; ++ks) {
            acc0 = __builtin_amdgcn_mfma_f32_32x32x16_bf16(ah[ks], bh[0][ks], acc0, 0, 0, 0);
            acc0 = __builtin_amdgcn_mfma_f32_32x32x16_bf16(ah[ks], bl8[0][ks], acc0, 0, 0, 0);
            acc0 = __builtin_amdgcn_mfma_f32_32x32x16_bf16(al8[ks], bh[0][ks], acc0, 0, 0, 0);
            acc1 = __builtin_amdgcn_mfma_f32_32x32x16_bf16(ah[ks], bh[1][ks], acc1, 0, 0, 0);
            acc1 = __builtin_amdgcn_mfma_f32_32x32x16_bf16(ah[ks], bl8[1][ks], acc1, 0, 0, 0);
            acc1 = __builtin_amdgcn_mfma_f32_32x32x16_bf16(al8[ks], bh[1][ks], acc1, 0, 0, 0);
        }
        __syncthreads();
        cur ^= 1;
    }

    // ---- epilogue ----
    const int fglob = khead * FO + wc * 64 + c;
    float b0 = bias[fglob], b1 = bias[fglob + 32];
#pragma unroll
    for (int r = 0; r < 16; ++r) { acc0[r] += b0; acc1[r] += b1; }

    float alv0 = aL[fglob], alv1 = aL[fglob + 32];
    float arv0 = aR[fglob], arv1 = aR[fglob + 32];
    float pl[16], pr[16];
#pragma unroll
    for (int r = 0; r < 16; ++r) {
        pl[r] = acc0[r] * alv0 + acc1[r] * alv1;
        pr[r] = acc0[r] * arv0 + acc1[r] * arv1;
    }
#pragma unroll
    for (int off = 1; off < 32; off <<= 1) {
#pragma unroll
        for (int r = 0; r < 16; ++r) {
            pl[r] += __shfl_xor(pl[r], off);
            pr[r] += __shfl_xor(pr[r], off);
        }
    }

    u16* T = &S[0][0];
    float* LRf = (float*)&S[0][0] + 9216;

    if (c == 0) {
#pragma unroll
        for (int r = 0; r < 16; ++r) {
            int node = wr * 32 + (r & 3) + 8 * (r >> 2) + 4 * half;
            LRf[(wc * 2 + 0) * 128 + node] = pl[r];
            LRf[(wc * 2 + 1) * 128 + node] = pr[r];
        }
    }

#pragma unroll
    for (int q = 0; q < 4; ++q) {
        int nb = wr * 32 + q * 8 + 4 * half;
        unsigned p00 = pk_bf16(acc0[q * 4 + 0], acc0[q * 4 + 1]);
        unsigned p01 = pk_bf16(acc0[q * 4 + 2], acc0[q * 4 + 3]);
        unsigned p10 = pk_bf16(acc1[q * 4 + 0], acc1[q * 4 + 1]);
        unsigned p11 = pk_bf16(acc1[q * 4 + 2], acc1[q * 4 + 3]);
        *(unsigned*)&T[(wc * 64 + c) * 136 + nb]      = p00;
        *(unsigned*)&T[(wc * 64 + c) * 136 + nb + 2]  = p01;
        *(unsigned*)&T[(wc * 64 + 32 + c) * 136 + nb]     = p10;
        *(unsigned*)&T[(wc * 64 + 32 + c) * 136 + nb + 2] = p11;
    }
    __syncthreads();

    // factor tables: C2 = (exp2(L2E*l), exp2(0.2*L2E*l)); D2 likewise for r
    if (wc == 0) {
        int node = wr * 32 + (lane & 31);
        if (lane < 32) {
            float L = (LRf[0 * 128 + node] + LRf[2 * 128 + node]) * LOG2E;
            float2 cv; cv.x = exp2f(L); cv.y = exp2f(0.2f * L);
            C2[(size_t)khead * N_NODES + n0 + node] = cv;
        } else {
            float R = (LRf[1 * 128 + node] + LRf[3 * 128 + node]) * LOG2E;
            float2 dv; dv.x = exp2f(R); dv.y = exp2f(0.2f * R);
            D2[(size_t)khead * N_NODES + n0 + node] = dv;
        }
    }

    {
        int f = tid >> 2, q = tid & 3;
        const uint4* src = (const uint4*)&T[f * 136 + q * 32];
        uint4* dst = (uint4*)(HbT + (size_t)(khead * FO + f) * N_NODES + n0 + q * 32);
#pragma unroll
        for (int u = 0; u < 4; ++u) dst[u] = src[u];
    }
}

// ---------------- Kernel D: pack mask (int32 0/1) into bitmask ----------------
__global__ __launch_bounds__(256) void pack_mask(const int* __restrict__ mask,
                                                 unsigned long long* __restrict__ mb) {
    int gid = blockIdx.x * 256 + threadIdx.x;
    int wid = gid >> 6, lane = gid & 63;
    int v = mask[(size_t)wid * 64 + lane];
    unsigned long long bits = __ballot(v != 0);
    if (lane == 0) mb[wid] = bits;
}

// ---------------- Kernel C: flash-style masked softmax + PV aggregation ----------------
// grid (64, 8), 512 threads = 8 waves: wg = w&3 -> 16-row n-slice, g = w>>2 -> m-half.
// P[n][m] = mask ? max(c_n*d_m, c'_n*d'_m) : 0   (factored exp, no transcendentals)
// Issue-order discipline (vmcnt FIFO): D/mask loads FIRST, then next-tile stage,
// so the compiler's wait-before-P-gen is vmcnt(4) (stage stays in flight), and the
// end-of-iter __syncthreads drain finds the stage already landed.
__global__ __launch_bounds__(512) void gat_attn(const u16* __restrict__ HbT,
                                                const float2* __restrict__ C2,
                                                const float2* __restrict__ D2,
                                                const unsigned long long* __restrict__ mb,
                                                float* __restrict__ out) {
    const int k = blockIdx.y;
    const int n0 = blockIdx.x * 64;
    const int tid = threadIdx.x;
    const int w = tid >> 6, lane = tid & 63;
    const int g = w >> 2, wg = w & 3;
    const int fr = lane & 15, kg = lane >> 4;

    __shared__ u16 Ht[2][2][128 * 64];   // [m-group][buf][tile] = 64 KB

    const int n_a = n0 + wg * 16 + fr;
    const float2 ccf = C2[(size_t)k * N_NODES + n_a];
    f32x2 cc; cc.x = ccf.x; cc.y = ccf.y;
    const unsigned long long* mrow = mb + (size_t)n_a * 64 + g * 32;

    f32x4 acc[9];
#pragma unroll
    for (int c = 0; c < 9; ++c) acc[c] = 0.f;

    const short o1 = (fr == 0) ? (short)0x3F80 : (short)0;
    const short8 ones = {o1, o1, o1, o1, o1, o1, o1, o1};

    const int fsub = lane >> 3;
    const int seg = ((lane & 7) ^ fsub) * 8;
    const u16* gstage = HbT + (size_t)(k * FO + wg * 32 + fsub) * N_NODES + g * 2048 + seg;
    u16* lb0 = &Ht[g][0][wg * 2048];
    u16* lb1 = &Ht[g][1][wg * 2048];

    const int frx = fr & 7;
    const int off0 = fr * 64 + (kg ^ frx) * 8;
    const int off1 = fr * 64 + ((kg + 4) ^ frx) * 8;

    const float2* D2k = D2 + (size_t)k * N_NODES + g * 2048 + kg * 8;

#pragma unroll
    for (int j = 0; j < 4; ++j)
        gload16(gstage + (size_t)j * 8 * N_NODES, lb0 + j * 512);
    __syncthreads();

    int cur = 0;
    for (int mt = 0; mt < 32; ++mt) {
        const int m0 = mt * 64;

        // (1) D factor + mask loads for THIS tile — issued BEFORE the prefetch so
        // their completion wait (vmcnt(4)) leaves the stage loads in flight.
        union { float4 f4[4]; f32x2 f2[8]; } Da, Db;
        {
            const float4* dva = (const float4*)(D2k + m0);
            const float4* dvb = (const float4*)(D2k + m0 + 32);
#pragma unroll
            for (int i = 0; i < 4; ++i) { Da.f4[i] = dva[i]; Db.f4[i] = dvb[i]; }
        }
        unsigned long long bits = mrow[mt];
        __builtin_amdgcn_sched_barrier(0);

        // (2) stage next tile into the other buffer (has the whole compute to land)
        if (mt < 31) {
            u16* nb = cur ? lb0 : lb1;
            const u16* gs = gstage + m0 + 64;
#pragma unroll
            for (int j = 0; j < 4; ++j)
                gload16(gs + (size_t)j * 8 * N_NODES, nb + j * 512);
        }
        __builtin_amdgcn_sched_barrier(0);

        // (3) P-gen
        unsigned m32a = (unsigned)(bits >> (kg * 8));
        unsigned m32b = (unsigned)(bits >> (kg * 8 + 32));
        float p0[8], p1[8];
#pragma unroll
        for (int v = 0; v < 8; ++v) {
            float pa = pkmul_max(cc, Da.f2[v]);
            unsigned sa2 = (unsigned)(((int)(m32a << (31 - v))) >> 31);
            p0[v] = __uint_as_float(__float_as_uint(pa) & sa2);
            float pb = pkmul_max(cc, Db.f2[v]);
            unsigned sb2 = (unsigned)(((int)(m32b << (31 - v))) >> 31);
            p1[v] = __uint_as_float(__float_as_uint(pb) & sb2);
        }
        union { unsigned u[4]; short8 s; } ua, ub;
#pragma unroll
        for (int vp = 0; vp < 4; ++vp) {
            ua.u[vp] = pk_bf16(p0[2 * vp], p0[2 * vp + 1]);
            ub.u[vp] = pk_bf16(p1[2 * vp], p1[2 * vp + 1]);
        }
        short8 a0 = ua.s, a1 = ub.s;

        // (4) MFMAs
        const u16* hb = &Ht[g][cur][0];
#pragma unroll
        for (int c = 0; c < 8; ++c) {
            short8 b0 = *(const short8*)(hb + c * 1024 + off0);
            short8 b1 = *(const short8*)(hb + c * 1024 + off1);
            acc[c] = __builtin_amdgcn_mfma_f32_16x16x32_bf16(a0, b0, acc[c], 0, 0, 0);
            acc[c] = __builtin_amdgcn_mfma_f32_16x16x32_bf16(a1, b1, acc[c], 0, 0, 0);
        }
        acc[8] = __builtin_amdgcn_mfma_f32_16x16x32_bf16(a0, ones, acc[8], 0, 0, 0);
        acc[8] = __builtin_amdgcn_mfma_f32_16x16x32_bf16(a1, ones, acc[8], 0, 0, 0);

        __syncthreads();
        cur ^= 1;
    }

    float* cmb = (float*)&Ht[0][0][0];
    if (g == 1) {
        float* base = cmb + wg * (36 * 64);
#pragma unroll
        for (int c = 0; c < 9; ++c)
#pragma unroll
            for (int j = 0; j < 4; ++j) base[(c * 4 + j) * 64 + lane] = acc[c][j];
    }
    __syncthreads();
    if (g == 0) {
        const float* base = cmb + wg * (36 * 64);
#pragma unroll
        for (int c = 0; c < 9; ++c)
#pragma unroll
            for (int j = 0; j < 4; ++j) acc[c][j] += base[(c * 4 + j) * 64 + lane];

#pragma unroll
        for (int j = 0; j < 4; ++j) {
            float S = __shfl(acc[8][j], (lane & 48));
            float inv = 1.0f / S;
            int n_out = n0 + wg * 16 + kg * 4 + j;
            float* orow = out + (size_t)n_out * DM + k * FO + fr;
#pragma unroll
            for (int c = 0; c < 8; ++c) {
                float v = acc[c][j] * inv;
                float e = v > 0.f ? v : (__expf(v) - 1.0f);
                orow[c * 16] = e;
            }
        }
    }
}

extern "C" void kernel_launch(void* const* d_in, const int* in_sizes, int n_in,
                              void* d_out, int out_size, void* d_ws, size_t ws_size,
                              hipStream_t stream) {
    const float* x = (const float*)d_in[0];
    const int* mask = (const int*)d_in[1];
    const float* W = (const float*)d_in[2];
    const float* bias = (const float*)d_in[3];
    const float* aL = (const float*)d_in[4];
    const float* aR = (const float*)d_in[5];
    float* out = (float*)d_out;

    char* ws = (char*)d_ws;
    u16* Xh = (u16*)ws;   ws += (size_t)N_NODES * FIN * 2;   // 4.19 MB
    u16* Xl = (u16*)ws;   ws += (size_t)N_NODES * FIN * 2;   // 4.19 MB
    u16* Wh = (u16*)ws;   ws += (size_t)DM * FIN * 2;        // 1.05 MB
    u16* Wl = (u16*)ws;   ws += (size_t)DM * FIN * 2;        // 1.05 MB
    u16* HbT = (u16*)ws;  ws += (size_t)KH * FO * N_NODES * 2; // 8.39 MB
    float2* C2 = (float2*)ws;  ws += (size_t)KH * N_NODES * 8;  // 256 KB
    float2* D2 = (float2*)ws;  ws += (size_t)KH * N_NODES * 8;  // 256 KB
    unsigned long long* mb = (unsigned long long*)ws;        // 2 MB

    split_bf16<<<dim3(2048), dim3(256), 0, stream>>>(x, Xh, Xl, N_NODES * FIN / 4);
    split_bf16<<<dim3(512), dim3(256), 0, stream>>>(W, Wh, Wl, DM * FIN / 4);
    gemm_mfma<<<dim3(8, 32), dim3(512), 0, stream>>>(Xh, Xl, Wh, Wl, bias, aL, aR,
                                                     C2, D2, HbT);
    pack_mask<<<dim3(65536), dim3(256), 0, stream>>>(mask, mb);
    gat_attn<<<dim3(64, 8), dim3(512), 0, stream>>>(HbT, C2, D2, mb, out);
}

// Round 7
// 131.722 us; speedup vs baseline: 1.7858x; 1.0094x over previous
//
#include <hip/hip_runtime.h>
#include <hip/hip_bf16.h>

typedef unsigned short u16;
typedef __attribute__((ext_vector_type(8))) short short8;
typedef __attribute__((ext_vector_type(2))) float f32x2;
typedef __attribute__((ext_vector_type(4))) float f32x4;
typedef __attribute__((ext_vector_type(16))) float f32x16;

#define N_NODES 4096
#define FIN 512
#define KH 8
#define FO 128
#define DM 1024   // KH*FO
#define LOG2E 1.44269504088896340736f

__device__ __forceinline__ void gload16(const u16* g, u16* l) {
    __builtin_amdgcn_global_load_lds(
        (const __attribute__((address_space(1))) unsigned int*)g,
        (__attribute__((address_space(3))) unsigned int*)l,
        16, 0, 0);
}

__device__ __forceinline__ unsigned pk_bf16(float lo, float hi) {
    unsigned r;
    asm("v_cvt_pk_bf16_f32 %0, %1, %2" : "=v"(r) : "v"(lo), "v"(hi));
    return r;
}

// (c*d, c'*d') in one packed-fp32 mul, then max of the two branches.
__device__ __forceinline__ float pkmul_max(f32x2 a, f32x2 b) {
    f32x2 r;
    asm("v_pk_mul_f32 %0, %1, %2" : "=v"(r) : "v"(a), "v"(b));
    return fmaxf(r.x, r.y);
}

// ---------------- Kernel P: split fp32 -> (hi, lo) bf16 ----------------
__global__ __launch_bounds__(256) void split_bf16(const float* __restrict__ src,
                                                  u16* __restrict__ hi,
                                                  u16* __restrict__ lo,
                                                  int n4) {
    int idx = blockIdx.x * 256 + threadIdx.x;
    if (idx >= n4) return;
    float4 v = ((const float4*)src)[idx];
    unsigned h01 = pk_bf16(v.x, v.y);
    unsigned h23 = pk_bf16(v.z, v.w);
    float hx = __uint_as_float(h01 << 16);
    float hy = __uint_as_float(h01 & 0xffff0000u);
    float hz = __uint_as_float(h23 << 16);
    float hw = __uint_as_float(h23 & 0xffff0000u);
    unsigned l01 = pk_bf16(v.x - hx, v.y - hy);
    unsigned l23 = pk_bf16(v.z - hz, v.w - hw);
    uint2 hv; hv.x = h01; hv.y = h23;
    uint2 lv; lv.x = l01; lv.y = l23;
    ((uint2*)hi)[idx] = hv;
    ((uint2*)lo)[idx] = lv;
}

// ---------------- Kernel A: MFMA split-bf16 GEMM + bias + C/D factor tables + transpose ----
__global__ __launch_bounds__(512) void gemm_mfma(const u16* __restrict__ Xh,
                                                 const u16* __restrict__ Xl,
                                                 const u16* __restrict__ Wh,
                                                 const u16* __restrict__ Wl,
                                                 const float* __restrict__ bias,
                                                 const float* __restrict__ aL,
                                                 const float* __restrict__ aR,
                                                 float2* __restrict__ C2,
                                                 unsigned* __restrict__ D2b,
                                                 u16* __restrict__ HbT) {
    const int khead = blockIdx.x;
    const int n0 = blockIdx.y * 128;
    const int tid = threadIdx.x;
    const int w = tid >> 6, lane = tid & 63;
    const int wr = w >> 1, wc = w & 1;
    const int c = lane & 31, half = lane >> 5;

    __shared__ u16 S[2][16384];

    const int sa = w >> 1;
    const int shv = w & 1;
    const int scl = lane & 3;
    const int ssw = ((lane >> 2) ^ (lane >> 4)) & 3;
    const int sgc = scl ^ ssw;
    const u16* gb; int growbase;
    if (sa == 0)      { gb = Xh; growbase = n0; }
    else if (sa == 1) { gb = Xl; growbase = n0; }
    else if (sa == 2) { gb = Wh; growbase = khead * 128; }
    else              { gb = Wl; growbase = khead * 128; }
    const u16* glb = gb + (size_t)(growbase + shv * 64 + (lane >> 2)) * FIN + sgc * 8;
    const int sldsoff = sa * 4096 + shv * 64 * 32;

    const int sw = ((c) ^ (c >> 2)) & 3;
    const int aoff = (wr * 32 + c) * 32;
    const int boff0 = 8192 + (wc * 64 + c) * 32;
    const int boff1 = 8192 + (wc * 64 + 32 + c) * 32;

    f32x16 acc0, acc1;
#pragma unroll
    for (int i = 0; i < 16; ++i) { acc0[i] = 0.f; acc1[i] = 0.f; }

#pragma unroll
    for (int i = 0; i < 4; ++i)
        gload16(glb + (size_t)i * 16 * FIN, &S[0][sldsoff + i * 512]);
    __syncthreads();

    int cur = 0;
    for (int kt = 0; kt < 16; ++kt) {
        if (kt < 15) {
            const u16* gsrc = glb + (kt + 1) * 32;
            u16* dst = &S[cur ^ 1][sldsoff];
#pragma unroll
            for (int i = 0; i < 4; ++i)
                gload16(gsrc + (size_t)i * 16 * FIN, dst + i * 512);
        }

        const u16* sp = S[cur];
        short8 ah[2], al8[2], bh[2][2], bl8[2][2];
#pragma unroll
        for (int ks = 0; ks < 2; ++ks) {
            int ch = ((ks * 2 + half) ^ sw) * 8;
            ah[ks]     = *(const short8*)&sp[aoff + ch];
            al8[ks]    = *(const short8*)&sp[4096 + aoff + ch];
            bh[0][ks]  = *(const short8*)&sp[boff0 + ch];
            bl8[0][ks] = *(const short8*)&sp[boff0 + 4096 + ch];
            bh[1][ks]  = *(const short8*)&sp[boff1 + ch];
            bl8[1][ks] = *(const short8*)&sp[boff1 + 4096 + ch];
        }
#pragma unroll
        for (int ks = 0; ks < 2; ++ks) {
            acc0 = __builtin_amdgcn_mfma_f32_32x32x16_bf16(ah[ks], bh[0][ks], acc0, 0, 0, 0);
            acc0 = __builtin_amdgcn_mfma_f32_32x32x16_bf16(ah[ks], bl8[0][ks], acc0, 0, 0, 0);
            acc0 = __builtin_amdgcn_mfma_f32_32x32x16_bf16(al8[ks], bh[0][ks], acc0, 0, 0, 0);
            acc1 = __builtin_amdgcn_mfma_f32_32x32x16_bf16(ah[ks], bh[1][ks], acc1, 0, 0, 0);
            acc1 = __builtin_amdgcn_mfma_f32_32x32x16_bf16(ah[ks], bl8[1][ks], acc1, 0, 0, 0);
            acc1 = __builtin_amdgcn_mfma_f32_32x32x16_bf16(al8[ks], bh[1][ks], acc1, 0, 0, 0);
        }
        __syncthreads();
        cur ^= 1;
    }

    const int fglob = khead * FO + wc * 64 + c;
    float b0 = bias[fglob], b1 = bias[fglob + 32];
#pragma unroll
    for (int r = 0; r < 16; ++r) { acc0[r] += b0; acc1[r] += b1; }

    float alv0 = aL[fglob], alv1 = aL[fglob + 32];
    float arv0 = aR[fglob], arv1 = aR[fglob + 32];
    float pl[16], pr[16];
#pragma unroll
    for (int r = 0; r < 16; ++r) {
        pl[r] = acc0[r] * alv0 + acc1[r] * alv1;
        pr[r] = acc0[r] * arv0 + acc1[r] * arv1;
    }
#pragma unroll
    for (int off = 1; off < 32; off <<= 1) {
#pragma unroll
        for (int r = 0; r < 16; ++r) {
            pl[r] += __shfl_xor(pl[r], off);
            pr[r] += __shfl_xor(pr[r], off);
        }
    }

    u16* T = &S[0][0];
    float* LRf = (float*)&S[0][0] + 9216;

    if (c == 0) {
#pragma unroll
        for (int r = 0; r < 16; ++r) {
            int node = wr * 32 + (r & 3) + 8 * (r >> 2) + 4 * half;
            LRf[(wc * 2 + 0) * 128 + node] = pl[r];
            LRf[(wc * 2 + 1) * 128 + node] = pr[r];
        }
    }

#pragma unroll
    for (int q = 0; q < 4; ++q) {
        int nb = wr * 32 + q * 8 + 4 * half;
        unsigned p00 = pk_bf16(acc0[q * 4 + 0], acc0[q * 4 + 1]);
        unsigned p01 = pk_bf16(acc0[q * 4 + 2], acc0[q * 4 + 3]);
        unsigned p10 = pk_bf16(acc1[q * 4 + 0], acc1[q * 4 + 1]);
        unsigned p11 = pk_bf16(acc1[q * 4 + 2], acc1[q * 4 + 3]);
        *(unsigned*)&T[(wc * 64 + c) * 136 + nb]      = p00;
        *(unsigned*)&T[(wc * 64 + c) * 136 + nb + 2]  = p01;
        *(unsigned*)&T[(wc * 64 + 32 + c) * 136 + nb]     = p10;
        *(unsigned*)&T[(wc * 64 + 32 + c) * 136 + nb + 2] = p11;
    }
    __syncthreads();

    // factor tables: C2 = (exp2(L2E*l), exp2(0.2*L2E*l)) fp32; D2b = packed bf16 pair
    if (wc == 0) {
        int node = wr * 32 + (lane & 31);
        if (lane < 32) {
            float L = (LRf[0 * 128 + node] + LRf[2 * 128 + node]) * LOG2E;
            float2 cv; cv.x = exp2f(L); cv.y = exp2f(0.2f * L);
            C2[(size_t)khead * N_NODES + n0 + node] = cv;
        } else {
            float R = (LRf[1 * 128 + node] + LRf[3 * 128 + node]) * LOG2E;
            D2b[(size_t)khead * N_NODES + n0 + node] = pk_bf16(exp2f(R), exp2f(0.2f * R));
        }
    }

    {
        int f = tid >> 2, q = tid & 3;
        const uint4* src = (const uint4*)&T[f * 136 + q * 32];
        uint4* dst = (uint4*)(HbT + (size_t)(khead * FO + f) * N_NODES + n0 + q * 32);
#pragma unroll
        for (int u = 0; u < 4; ++u) dst[u] = src[u];
    }
}

// ---------------- Kernel D: pack mask (int32 0/1) into bitmask ----------------
__global__ __launch_bounds__(256) void pack_mask(const int* __restrict__ mask,
                                                 unsigned long long* __restrict__ mb) {
    int gid = blockIdx.x * 256 + threadIdx.x;
    int wid = gid >> 6, lane = gid & 63;
    int v = mask[(size_t)wid * 64 + lane];
    unsigned long long bits = __ballot(v != 0);
    if (lane == 0) mb[wid] = bits;
}

// ---------------- Kernel C: flash-style masked softmax + PV aggregation ----------------
// Flat grid 512: head = blk&7 (pins head<->XCD: per-XCD working set ~3.1MB, L2-fit),
// nb = blk>>3. 512 thr = 8 waves: wg = w&3 (16-row n-slice), g = w>>2 (m-half).
// Counted-vmcnt double-barrier pipeline, prefetch distance 2, never vmcnt(0) in loop.
__device__ __forceinline__ void pgen(f32x2 cc, uint4 a0v, uint4 a1v, uint4 b0v, uint4 b1v,
                                     unsigned long long bits, int kg,
                                     short8& A0, short8& A1) {
    unsigned m32a = (unsigned)(bits >> (kg * 8));
    unsigned m32b = (unsigned)(bits >> (kg * 8 + 32));
    unsigned dua[8] = {a0v.x, a0v.y, a0v.z, a0v.w, a1v.x, a1v.y, a1v.z, a1v.w};
    unsigned dub[8] = {b0v.x, b0v.y, b0v.z, b0v.w, b1v.x, b1v.y, b1v.z, b1v.w};
    float p0[8], p1[8];
#pragma unroll
    for (int v = 0; v < 8; ++v) {
        f32x2 dva; dva.x = __uint_as_float(dua[v] << 16);
        dva.y = __uint_as_float(dua[v] & 0xffff0000u);
        float pa = pkmul_max(cc, dva);
        unsigned sa2 = (unsigned)(((int)(m32a << (31 - v))) >> 31);
        p0[v] = __uint_as_float(__float_as_uint(pa) & sa2);
        f32x2 dvb; dvb.x = __uint_as_float(dub[v] << 16);
        dvb.y = __uint_as_float(dub[v] & 0xffff0000u);
        float pb = pkmul_max(cc, dvb);
        unsigned sb2 = (unsigned)(((int)(m32b << (31 - v))) >> 31);
        p1[v] = __uint_as_float(__float_as_uint(pb) & sb2);
    }
    union { unsigned u[4]; short8 s; } ua, ub;
#pragma unroll
    for (int vp = 0; vp < 4; ++vp) {
        ua.u[vp] = pk_bf16(p0[2 * vp], p0[2 * vp + 1]);
        ub.u[vp] = pk_bf16(p1[2 * vp], p1[2 * vp + 1]);
    }
    A0 = ua.s; A1 = ub.s;
}

__global__ __launch_bounds__(512, 4) void gat_attn(const u16* __restrict__ HbT,
                                                   const float2* __restrict__ C2,
                                                   const unsigned* __restrict__ D2b,
                                                   const unsigned long long* __restrict__ mb,
                                                   float* __restrict__ out) {
    const int blk = blockIdx.x;
    const int k = blk & 7;               // head == XCD
    const int n0 = (blk >> 3) * 64;
    const int tid = threadIdx.x;
    const int w = tid >> 6, lane = tid & 63;
    const int g = w >> 2, wg = w & 3;
    const int fr = lane & 15, kg = lane >> 4;

    __shared__ u16 Ht[2][2][128 * 64];   // [m-group][buf][tile] = 64 KB

    const int n_a = n0 + wg * 16 + fr;
    const float2 ccf = C2[(size_t)k * N_NODES + n_a];
    f32x2 cc; cc.x = ccf.x; cc.y = ccf.y;
    const unsigned long long* mrow = mb + (size_t)n_a * 64 + g * 32;

    f32x4 acc[9];
#pragma unroll
    for (int c = 0; c < 9; ++c) acc[c] = 0.f;

    const short o1 = (fr == 0) ? (short)0x3F80 : (short)0;
    const short8 ones = {o1, o1, o1, o1, o1, o1, o1, o1};

    const int fsub = lane >> 3;
    const int seg = ((lane & 7) ^ fsub) * 8;
    const u16* gstage = HbT + (size_t)(k * FO + wg * 32 + fsub) * N_NODES + g * 2048 + seg;
    u16* lb0 = &Ht[g][0][wg * 2048];
    u16* lb1 = &Ht[g][1][wg * 2048];

    const int frx = fr & 7;
    const int off0 = fr * 64 + (kg ^ frx) * 8;
    const int off1 = fr * 64 + ((kg + 4) ^ frx) * 8;

    const unsigned* D2k = D2b + (size_t)k * N_NODES + g * 2048 + kg * 8;

    // ---- prologue: D(0)+mask(0), stage T0, T1; wait T0; barrier ----
    uint4 dA0, dA1, dB0, dB1, eA0, eA1, eB0, eB1;
    unsigned long long bc, bn;
    dA0 = *(const uint4*)(D2k);      dA1 = *(const uint4*)(D2k + 4);
    dB0 = *(const uint4*)(D2k + 32); dB1 = *(const uint4*)(D2k + 36);
    bc = mrow[0];
    __builtin_amdgcn_sched_barrier(0);
#pragma unroll
    for (int j = 0; j < 4; ++j)
        gload16(gstage + (size_t)j * 8 * N_NODES, lb0 + j * 512);
    __builtin_amdgcn_sched_barrier(0);
#pragma unroll
    for (int j = 0; j < 4; ++j)
        gload16(gstage + 64 + (size_t)j * 8 * N_NODES, lb1 + j * 512);
    __builtin_amdgcn_sched_barrier(0);
    asm volatile("s_waitcnt vmcnt(4)" ::: "memory");
    __builtin_amdgcn_sched_barrier(0);
    __builtin_amdgcn_s_barrier();
    __builtin_amdgcn_sched_barrier(0);

// Per-iteration: P-gen(D_cur) | issue D_next(5) | MFMA from buf | lgkm0+bar#1 |
// stage T+2 into just-read buf (4) | vmcnt(9) retires T+1 | bar#2.
#define ATTN_STEP(BUF, MT, DA0,DA1,DB0,DB1,BITS, NA0,NA1,NB0,NB1,NBITS)  do {          \
    short8 a0, a1;                                                                      \
    pgen(cc, DA0, DA1, DB0, DB1, BITS, kg, a0, a1);                                     \
    __builtin_amdgcn_sched_barrier(0);                                                  \
    { const unsigned* dnp = D2k + ((((MT) + 1) & 31) << 6);                             \
      NA0 = *(const uint4*)(dnp);      NA1 = *(const uint4*)(dnp + 4);                  \
      NB0 = *(const uint4*)(dnp + 32); NB1 = *(const uint4*)(dnp + 36);                 \
      NBITS = mrow[((MT) + 1) & 31]; }                                                  \
    __builtin_amdgcn_sched_barrier(0);                                                  \
    { const u16* hb = &Ht[g][BUF][0];                                                   \
      _Pragma("unroll")                                                                 \
      for (int c = 0; c < 8; ++c) {                                                     \
          short8 b0 = *(const short8*)(hb + c * 1024 + off0);                           \
          short8 b1 = *(const short8*)(hb + c * 1024 + off1);                           \
          acc[c] = __builtin_amdgcn_mfma_f32_16x16x32_bf16(a0, b0, acc[c], 0, 0, 0);    \
          acc[c] = __builtin_amdgcn_mfma_f32_16x16x32_bf16(a1, b1, acc[c], 0, 0, 0);    \
      }                                                                                 \
      acc[8] = __builtin_amdgcn_mfma_f32_16x16x32_bf16(a0, ones, acc[8], 0, 0, 0);      \
      acc[8] = __builtin_amdgcn_mfma_f32_16x16x32_bf16(a1, ones, acc[8], 0, 0, 0); }    \
    asm volatile("s_waitcnt lgkmcnt(0)" ::: "memory");                                  \
    __builtin_amdgcn_sched_barrier(0);                                                  \
    __builtin_amdgcn_s_barrier();                                                       \
    __builtin_amdgcn_sched_barrier(0);                                                  \
    { const u16* gs = gstage + ((((MT) + 2) & 31) << 6);                                \
      u16* lbs = (BUF) ? lb1 : lb0;                                                     \
      _Pragma("unroll")                                                                 \
      for (int j = 0; j < 4; ++j)                                                       \
          gload16(gs + (size_t)j * 8 * N_NODES, lbs + j * 512); }                       \
    __builtin_amdgcn_sched_barrier(0);                                                  \
    asm volatile("s_waitcnt vmcnt(9)" ::: "memory");                                    \
    __builtin_amdgcn_sched_barrier(0);                                                  \
    __builtin_amdgcn_s_barrier();                                                       \
    __builtin_amdgcn_sched_barrier(0);                                                  \
} while (0)

    for (int mt = 0; mt < 32; mt += 2) {
        ATTN_STEP(0, mt,     dA0, dA1, dB0, dB1, bc,  eA0, eA1, eB0, eB1, bn);
        ATTN_STEP(1, mt + 1, eA0, eA1, eB0, eB1, bn,  dA0, dA1, dB0, dB1, bc);
    }
#undef ATTN_STEP

    __syncthreads();   // full drain: stray wrap-staged DMAs must land before LDS reuse

    float* cmb = (float*)&Ht[0][0][0];
    if (g == 1) {
        float* base = cmb + wg * (36 * 64);
#pragma unroll
        for (int c = 0; c < 9; ++c)
#pragma unroll
            for (int j = 0; j < 4; ++j) base[(c * 4 + j) * 64 + lane] = acc[c][j];
    }
    __syncthreads();
    if (g == 0) {
        const float* base = cmb + wg * (36 * 64);
#pragma unroll
        for (int c = 0; c < 9; ++c)
#pragma unroll
            for (int j = 0; j < 4; ++j) acc[c][j] += base[(c * 4 + j) * 64 + lane];

#pragma unroll
        for (int j = 0; j < 4; ++j) {
            float S = __shfl(acc[8][j], (lane & 48));
            float inv = 1.0f / S;
            int n_out = n0 + wg * 16 + kg * 4 + j;
            float* orow = out + (size_t)n_out * DM + k * FO + fr;
#pragma unroll
            for (int c = 0; c < 8; ++c) {
                float v = acc[c][j] * inv;
                float e = v > 0.f ? v : (__expf(v) - 1.0f);
                orow[c * 16] = e;
            }
        }
    }
}

extern "C" void kernel_launch(void* const* d_in, const int* in_sizes, int n_in,
                              void* d_out, int out_size, void* d_ws, size_t ws_size,
                              hipStream_t stream) {
    const float* x = (const float*)d_in[0];
    const int* mask = (const int*)d_in[1];
    const float* W = (const float*)d_in[2];
    const float* bias = (const float*)d_in[3];
    const float* aL = (const float*)d_in[4];
    const float* aR = (const float*)d_in[5];
    float* out = (float*)d_out;

    char* ws = (char*)d_ws;
    u16* Xh = (u16*)ws;   ws += (size_t)N_NODES * FIN * 2;   // 4.19 MB
    u16* Xl = (u16*)ws;   ws += (size_t)N_NODES * FIN * 2;   // 4.19 MB
    u16* Wh = (u16*)ws;   ws += (size_t)DM * FIN * 2;        // 1.05 MB
    u16* Wl = (u16*)ws;   ws += (size_t)DM * FIN * 2;        // 1.05 MB
    u16* HbT = (u16*)ws;  ws += (size_t)KH * FO * N_NODES * 2; // 8.39 MB
    float2* C2 = (float2*)ws;  ws += (size_t)KH * N_NODES * 8;  // 256 KB
    unsigned* D2b = (unsigned*)ws; ws += (size_t)KH * N_NODES * 4; // 128 KB
    unsigned long long* mb = (unsigned long long*)ws;        // 2 MB

    split_bf16<<<dim3(2048), dim3(256), 0, stream>>>(x, Xh, Xl, N_NODES * FIN / 4);
    split_bf16<<<dim3(512), dim3(256), 0, stream>>>(W, Wh, Wl, DM * FIN / 4);
    gemm_mfma<<<dim3(8, 32), dim3(512), 0, stream>>>(Xh, Xl, Wh, Wl, bias, aL, aR,
                                                     C2, D2b, HbT);
    pack_mask<<<dim3(65536), dim3(256), 0, stream>>>(mask, mb);
    gat_attn<<<dim3(512), dim3(512), 0, stream>>>(HbT, C2, D2b, mb, out);
}

// Round 8
// 126.885 us; speedup vs baseline: 1.8539x; 1.0381x over previous
//
#include <hip/hip_runtime.h>
#include <hip/hip_bf16.h>

typedef unsigned short u16;
typedef __attribute__((ext_vector_type(8))) short short8;
typedef __attribute__((ext_vector_type(4))) float f32x4;
typedef __attribute__((ext_vector_type(16))) float f32x16;

#define N_NODES 4096
#define FIN 512
#define KH 8
#define FO 128
#define DM 1024   // KH*FO
#define LOG2E 1.44269504088896340736f

__device__ __forceinline__ void gload16(const u16* g, u16* l) {
    __builtin_amdgcn_global_load_lds(
        (const __attribute__((address_space(1))) unsigned int*)g,
        (__attribute__((address_space(3))) unsigned int*)l,
        16, 0, 0);
}

__device__ __forceinline__ unsigned pk_bf16(float lo, float hi) {
    unsigned r;
    asm("v_cvt_pk_bf16_f32 %0, %1, %2" : "=v"(r) : "v"(lo), "v"(hi));
    return r;
}

// ---------------- Kernel P: split fp32 -> (hi, lo) bf16 ----------------
__global__ __launch_bounds__(256) void split_bf16(const float* __restrict__ src,
                                                  u16* __restrict__ hi,
                                                  u16* __restrict__ lo,
                                                  int n4) {
    int idx = blockIdx.x * 256 + threadIdx.x;
    if (idx >= n4) return;
    float4 v = ((const float4*)src)[idx];
    unsigned h01 = pk_bf16(v.x, v.y);
    unsigned h23 = pk_bf16(v.z, v.w);
    float hx = __uint_as_float(h01 << 16);
    float hy = __uint_as_float(h01 & 0xffff0000u);
    float hz = __uint_as_float(h23 << 16);
    float hw = __uint_as_float(h23 & 0xffff0000u);
    unsigned l01 = pk_bf16(v.x - hx, v.y - hy);
    unsigned l23 = pk_bf16(v.z - hz, v.w - hw);
    uint2 hv; hv.x = h01; hv.y = h23;
    uint2 lv; lv.x = l01; lv.y = l23;
    ((uint2*)hi)[idx] = hv;
    ((uint2*)lo)[idx] = lv;
}

// ---------------- Kernel A: MFMA split-bf16 GEMM + bias + C/D factor tables + transpose ----
__global__ __launch_bounds__(512) void gemm_mfma(const u16* __restrict__ Xh,
                                                 const u16* __restrict__ Xl,
                                                 const u16* __restrict__ Wh,
                                                 const u16* __restrict__ Wl,
                                                 const float* __restrict__ bias,
                                                 const float* __restrict__ aL,
                                                 const float* __restrict__ aR,
                                                 float2* __restrict__ C2,
                                                 unsigned* __restrict__ D2b,
                                                 u16* __restrict__ HbT) {
    const int khead = blockIdx.x;
    const int n0 = blockIdx.y * 128;
    const int tid = threadIdx.x;
    const int w = tid >> 6, lane = tid & 63;
    const int wr = w >> 1, wc = w & 1;
    const int c = lane & 31, half = lane >> 5;

    __shared__ u16 S[2][16384];

    const int sa = w >> 1;
    const int shv = w & 1;
    const int scl = lane & 3;
    const int ssw = ((lane >> 2) ^ (lane >> 4)) & 3;
    const int sgc = scl ^ ssw;
    const u16* gb; int growbase;
    if (sa == 0)      { gb = Xh; growbase = n0; }
    else if (sa == 1) { gb = Xl; growbase = n0; }
    else if (sa == 2) { gb = Wh; growbase = khead * 128; }
    else              { gb = Wl; growbase = khead * 128; }
    const u16* glb = gb + (size_t)(growbase + shv * 64 + (lane >> 2)) * FIN + sgc * 8;
    const int sldsoff = sa * 4096 + shv * 64 * 32;

    const int sw = ((c) ^ (c >> 2)) & 3;
    const int aoff = (wr * 32 + c) * 32;
    const int boff0 = 8192 + (wc * 64 + c) * 32;
    const int boff1 = 8192 + (wc * 64 + 32 + c) * 32;

    f32x16 acc0, acc1;
#pragma unroll
    for (int i = 0; i < 16; ++i) { acc0[i] = 0.f; acc1[i] = 0.f; }

#pragma unroll
    for (int i = 0; i < 4; ++i)
        gload16(glb + (size_t)i * 16 * FIN, &S[0][sldsoff + i * 512]);
    __syncthreads();

    int cur = 0;
    for (int kt = 0; kt < 16; ++kt) {
        if (kt < 15) {
            const u16* gsrc = glb + (kt + 1) * 32;
            u16* dst = &S[cur ^ 1][sldsoff];
#pragma unroll
            for (int i = 0; i < 4; ++i)
                gload16(gsrc + (size_t)i * 16 * FIN, dst + i * 512);
        }

        const u16* sp = S[cur];
        short8 ah[2], al8[2], bh[2][2], bl8[2][2];
#pragma unroll
        for (int ks = 0; ks < 2; ++ks) {
            int ch = ((ks * 2 + half) ^ sw) * 8;
            ah[ks]     = *(const short8*)&sp[aoff + ch];
            al8[ks]    = *(const short8*)&sp[4096 + aoff + ch];
            bh[0][ks]  = *(const short8*)&sp[boff0 + ch];
            bl8[0][ks] = *(const short8*)&sp[boff0 + 4096 + ch];
            bh[1][ks]  = *(const short8*)&sp[boff1 + ch];
            bl8[1][ks] = *(const short8*)&sp[boff1 + 4096 + ch];
        }
#pragma unroll
        for (int ks = 0; ks < 2; ++ks) {
            acc0 = __builtin_amdgcn_mfma_f32_32x32x16_bf16(ah[ks], bh[0][ks], acc0, 0, 0, 0);
            acc0 = __builtin_amdgcn_mfma_f32_32x32x16_bf16(ah[ks], bl8[0][ks], acc0, 0, 0, 0);
            acc0 = __builtin_amdgcn_mfma_f32_32x32x16_bf16(al8[ks], bh[0][ks], acc0, 0, 0, 0);
            acc1 = __builtin_amdgcn_mfma_f32_32x32x16_bf16(ah[ks], bh[1][ks], acc1, 0, 0, 0);
            acc1 = __builtin_amdgcn_mfma_f32_32x32x16_bf16(ah[ks], bl8[1][ks], acc1, 0, 0, 0);
            acc1 = __builtin_amdgcn_mfma_f32_32x32x16_bf16(al8[ks], bh[1][ks], acc1, 0, 0, 0);
        }
        __syncthreads();
        cur ^= 1;
    }

    const int fglob = khead * FO + wc * 64 + c;
    float b0 = bias[fglob], b1 = bias[fglob + 32];
#pragma unroll
    for (int r = 0; r < 16; ++r) { acc0[r] += b0; acc1[r] += b1; }

    float alv0 = aL[fglob], alv1 = aL[fglob + 32];
    float arv0 = aR[fglob], arv1 = aR[fglob + 32];
    float pl[16], pr[16];
#pragma unroll
    for (int r = 0; r < 16; ++r) {
        pl[r] = acc0[r] * alv0 + acc1[r] * alv1;
        pr[r] = acc0[r] * arv0 + acc1[r] * arv1;
    }
#pragma unroll
    for (int off = 1; off < 32; off <<= 1) {
#pragma unroll
        for (int r = 0; r < 16; ++r) {
            pl[r] += __shfl_xor(pl[r], off);
            pr[r] += __shfl_xor(pr[r], off);
        }
    }

    u16* T = &S[0][0];
    float* LRf = (float*)&S[0][0] + 9216;

    if (c == 0) {
#pragma unroll
        for (int r = 0; r < 16; ++r) {
            int node = wr * 32 + (r & 3) + 8 * (r >> 2) + 4 * half;
            LRf[(wc * 2 + 0) * 128 + node] = pl[r];
            LRf[(wc * 2 + 1) * 128 + node] = pr[r];
        }
    }

#pragma unroll
    for (int q = 0; q < 4; ++q) {
        int nb = wr * 32 + q * 8 + 4 * half;
        unsigned p00 = pk_bf16(acc0[q * 4 + 0], acc0[q * 4 + 1]);
        unsigned p01 = pk_bf16(acc0[q * 4 + 2], acc0[q * 4 + 3]);
        unsigned p10 = pk_bf16(acc1[q * 4 + 0], acc1[q * 4 + 1]);
        unsigned p11 = pk_bf16(acc1[q * 4 + 2], acc1[q * 4 + 3]);
        *(unsigned*)&T[(wc * 64 + c) * 136 + nb]      = p00;
        *(unsigned*)&T[(wc * 64 + c) * 136 + nb + 2]  = p01;
        *(unsigned*)&T[(wc * 64 + 32 + c) * 136 + nb]     = p10;
        *(unsigned*)&T[(wc * 64 + 32 + c) * 136 + nb + 2] = p11;
    }
    __syncthreads();

    if (wc == 0) {
        int node = wr * 32 + (lane & 31);
        if (lane < 32) {
            float L = (LRf[0 * 128 + node] + LRf[2 * 128 + node]) * LOG2E;
            float2 cv; cv.x = exp2f(L); cv.y = exp2f(0.2f * L);
            C2[(size_t)khead * N_NODES + n0 + node] = cv;
        } else {
            float R = (LRf[1 * 128 + node] + LRf[3 * 128 + node]) * LOG2E;
            D2b[(size_t)khead * N_NODES + n0 + node] = pk_bf16(exp2f(R), exp2f(0.2f * R));
        }
    }

    {
        int f = tid >> 2, q = tid & 3;
        const uint4* src = (const uint4*)&T[f * 136 + q * 32];
        uint4* dst = (uint4*)(HbT + (size_t)(khead * FO + f) * N_NODES + n0 + q * 32);
#pragma unroll
        for (int u = 0; u < 4; ++u) dst[u] = src[u];
    }
}

// ---------------- Kernel D: pack mask (int32 0/1) into bitmask ----------------
__global__ __launch_bounds__(256) void pack_mask(const int* __restrict__ mask,
                                                 unsigned long long* __restrict__ mb) {
    int gid = blockIdx.x * 256 + threadIdx.x;
    int wid = gid >> 6, lane = gid & 63;
    int v = mask[(size_t)wid * 64 + lane];
    unsigned long long bits = __ballot(v != 0);
    if (lane == 0) mb[wid] = bits;
}

// ---------------- Kernel C: flash-style masked softmax + PV aggregation ----------------
// Flat grid 512: head = blk&7 (head<->XCD pin, L2-resident working set).
// ONE barrier per m-tile; stage(t+1) + D(t+1) issued at iteration START (targets the
// buffer whose readers all passed the previous barrier); compute phase has NO sched
// walls (compiler interleaves P-gen VALU with ds_read+MFMA); tail = lgkmcnt(0) +
// counted vmcnt(5) (retires stage, leaves D in flight) + s_barrier. Never vmcnt(0).
__global__ __launch_bounds__(512, 4) void gat_attn(const u16* __restrict__ HbT,
                                                   const float2* __restrict__ C2,
                                                   const unsigned* __restrict__ D2b,
                                                   const unsigned long long* __restrict__ mb,
                                                   float* __restrict__ out) {
    const int blk = blockIdx.x;
    const int k = blk & 7;
    const int n0 = (blk >> 3) * 64;
    const int tid = threadIdx.x;
    const int w = tid >> 6, lane = tid & 63;
    const int g = w >> 2, wg = w & 3;
    const int fr = lane & 15, kg = lane >> 4;

    __shared__ u16 Ht[2][2][128 * 64];   // [m-group][buf][tile] = 64 KB

    const int n_a = n0 + wg * 16 + fr;
    const float2 ccf = C2[(size_t)k * N_NODES + n_a];
    const float ccx = ccf.x, ccy = ccf.y;
    const unsigned long long* mrow = mb + (size_t)n_a * 64 + g * 32;
    const int shA = kg * 8, shB = shA + 32;

    f32x4 acc[9];
#pragma unroll
    for (int c = 0; c < 9; ++c) acc[c] = 0.f;

    const short o1 = (fr == 0) ? (short)0x3F80 : (short)0;
    const short8 ones = {o1, o1, o1, o1, o1, o1, o1, o1};

    const int fsub = lane >> 3;
    const int seg = ((lane & 7) ^ fsub) * 8;
    const u16* gstage = HbT + (size_t)(k * FO + wg * 32 + fsub) * N_NODES + g * 2048 + seg;
    u16* lb0 = &Ht[g][0][wg * 2048];
    u16* lb1 = &Ht[g][1][wg * 2048];

    const int frx = fr & 7;
    const int off0 = fr * 64 + (kg ^ frx) * 8;
    const int off1 = fr * 64 + ((kg + 4) ^ frx) * 8;

    const unsigned* D2k = D2b + (size_t)k * N_NODES + g * 2048 + kg * 8;

    // ---- prologue: stage(0)->lb0 [4], D(0) [5]; vmcnt(5) retires stage(0); barrier ----
    uint4 dc0, dc1, dc2, dc3;
    unsigned long long bc;
#pragma unroll
    for (int j = 0; j < 4; ++j)
        gload16(gstage + (size_t)j * 8 * N_NODES, lb0 + j * 512);
    dc0 = *(const uint4*)(D2k);      dc1 = *(const uint4*)(D2k + 4);
    dc2 = *(const uint4*)(D2k + 32); dc3 = *(const uint4*)(D2k + 36);
    bc = mrow[0];
    asm volatile("s_waitcnt vmcnt(5)" ::: "memory");
    __builtin_amdgcn_s_barrier();

// One half-iteration: reads RBUF (tile MT, factors DC*/BITS), stages tile MT+1 into
// SBUF, loads D(MT+1) into DN*/NBITS. Free-scheduled compute; counted-vmcnt tail.
#define ATTN_HALF(RBUF, SBUF, MT, DC0,DC1,DC2,DC3,BITS, DN0,DN1,DN2,DN3,NBITS) do {    \
    const unsigned nxt = ((MT) + 1) & 31;                                               \
    if ((MT) < 31) {                                                                    \
        const u16* gs = gstage + ((size_t)nxt << 6);                                    \
        _Pragma("unroll")                                                               \
        for (int j = 0; j < 4; ++j)                                                     \
            gload16(gs + (size_t)j * 8 * N_NODES, (SBUF) + j * 512);                    \
    }                                                                                   \
    { const unsigned* dnp = D2k + (nxt << 6);                                           \
      DN0 = *(const uint4*)(dnp);      DN1 = *(const uint4*)(dnp + 4);                  \
      DN2 = *(const uint4*)(dnp + 32); DN3 = *(const uint4*)(dnp + 36);                 \
      NBITS = mrow[nxt]; }                                                              \
    __builtin_amdgcn_sched_barrier(0);                                                  \
    {                                                                                   \
        unsigned m32a = (unsigned)((BITS) >> shA);                                      \
        unsigned m32b = (unsigned)((BITS) >> shB);                                      \
        unsigned wa[8] = {DC0.x, DC0.y, DC0.z, DC0.w, DC1.x, DC1.y, DC1.z, DC1.w};      \
        unsigned wb[8] = {DC2.x, DC2.y, DC2.z, DC2.w, DC3.x, DC3.y, DC3.z, DC3.w};      \
        float p0[8], p1[8];                                                             \
        _Pragma("unroll")                                                               \
        for (int v = 0; v < 8; ++v) {                                                   \
            float pa = fmaxf(ccx * __uint_as_float(wa[v] << 16),                        \
                             ccy * __uint_as_float(wa[v] & 0xffff0000u));               \
            unsigned sa2 = (unsigned)(((int)(m32a << (31 - v))) >> 31);                 \
            p0[v] = __uint_as_float(__float_as_uint(pa) & sa2);                         \
            float pb = fmaxf(ccx * __uint_as_float(wb[v] << 16),                        \
                             ccy * __uint_as_float(wb[v] & 0xffff0000u));               \
            unsigned sb2 = (unsigned)(((int)(m32b << (31 - v))) >> 31);                 \
            p1[v] = __uint_as_float(__float_as_uint(pb) & sb2);                         \
        }                                                                               \
        union { unsigned u[4]; short8 s; } ua, ub;                                      \
        _Pragma("unroll")                                                               \
        for (int vp = 0; vp < 4; ++vp) {                                                \
            ua.u[vp] = pk_bf16(p0[2 * vp], p0[2 * vp + 1]);                             \
            ub.u[vp] = pk_bf16(p1[2 * vp], p1[2 * vp + 1]);                             \
        }                                                                               \
        short8 a0 = ua.s, a1 = ub.s;                                                    \
        const u16* hb = (RBUF);                                                         \
        _Pragma("unroll")                                                               \
        for (int c = 0; c < 8; ++c) {                                                   \
            short8 b0 = *(const short8*)(hb + c * 1024 + off0);                         \
            short8 b1 = *(const short8*)(hb + c * 1024 + off1);                         \
            acc[c] = __builtin_amdgcn_mfma_f32_16x16x32_bf16(a0, b0, acc[c], 0, 0, 0);  \
            acc[c] = __builtin_amdgcn_mfma_f32_16x16x32_bf16(a1, b1, acc[c], 0, 0, 0);  \
        }                                                                               \
        acc[8] = __builtin_amdgcn_mfma_f32_16x16x32_bf16(a0, ones, acc[8], 0, 0, 0);    \
        acc[8] = __builtin_amdgcn_mfma_f32_16x16x32_bf16(a1, ones, acc[8], 0, 0, 0);    \
    }                                                                                   \
    asm volatile("s_waitcnt lgkmcnt(0)" ::: "memory");                                  \
    asm volatile("s_waitcnt vmcnt(5)" ::: "memory");                                    \
    __builtin_amdgcn_s_barrier();                                                       \
} while (0)

    {
        uint4 en0, en1, en2, en3;
        unsigned long long bn;
        // Group base LDS pointers for reads (wave reads the whole group tile)
        const u16* rb0 = &Ht[g][0][0];
        const u16* rb1 = &Ht[g][1][0];
        for (int mt = 0; mt < 32; mt += 2) {
            ATTN_HALF(rb0, lb1, mt,     dc0, dc1, dc2, dc3, bc, en0, en1, en2, en3, bn);
            ATTN_HALF(rb1, lb0, mt + 1, en0, en1, en2, en3, bn, dc0, dc1, dc2, dc3, bc);
        }
    }
#undef ATTN_HALF

    asm volatile("s_waitcnt vmcnt(0)" ::: "memory");
    __syncthreads();   // full drain before LDS reuse

    float* cmb = (float*)&Ht[0][0][0];
    if (g == 1) {
        float* base = cmb + wg * (36 * 64);
#pragma unroll
        for (int c = 0; c < 9; ++c)
#pragma unroll
            for (int j = 0; j < 4; ++j) base[(c * 4 + j) * 64 + lane] = acc[c][j];
    }
    __syncthreads();
    if (g == 0) {
        const float* base = cmb + wg * (36 * 64);
#pragma unroll
        for (int c = 0; c < 9; ++c)
#pragma unroll
            for (int j = 0; j < 4; ++j) acc[c][j] += base[(c * 4 + j) * 64 + lane];

#pragma unroll
        for (int j = 0; j < 4; ++j) {
            float S = __shfl(acc[8][j], (lane & 48));
            float inv = 1.0f / S;
            int n_out = n0 + wg * 16 + kg * 4 + j;
            float* orow = out + (size_t)n_out * DM + k * FO + fr;
#pragma unroll
            for (int c = 0; c < 8; ++c) {
                float v = acc[c][j] * inv;
                float e = v > 0.f ? v : (__expf(v) - 1.0f);
                orow[c * 16] = e;
            }
        }
    }
}

extern "C" void kernel_launch(void* const* d_in, const int* in_sizes, int n_in,
                              void* d_out, int out_size, void* d_ws, size_t ws_size,
                              hipStream_t stream) {
    const float* x = (const float*)d_in[0];
    const int* mask = (const int*)d_in[1];
    const float* W = (const float*)d_in[2];
    const float* bias = (const float*)d_in[3];
    const float* aL = (const float*)d_in[4];
    const float* aR = (const float*)d_in[5];
    float* out = (float*)d_out;

    char* ws = (char*)d_ws;
    u16* Xh = (u16*)ws;   ws += (size_t)N_NODES * FIN * 2;   // 4.19 MB
    u16* Xl = (u16*)ws;   ws += (size_t)N_NODES * FIN * 2;   // 4.19 MB
    u16* Wh = (u16*)ws;   ws += (size_t)DM * FIN * 2;        // 1.05 MB
    u16* Wl = (u16*)ws;   ws += (size_t)DM * FIN * 2;        // 1.05 MB
    u16* HbT = (u16*)ws;  ws += (size_t)KH * FO * N_NODES * 2; // 8.39 MB
    float2* C2 = (float2*)ws;  ws += (size_t)KH * N_NODES * 8;  // 256 KB
    unsigned* D2b = (unsigned*)ws; ws += (size_t)KH * N_NODES * 4; // 128 KB
    unsigned long long* mb = (unsigned long long*)ws;        // 2 MB

    split_bf16<<<dim3(2048), dim3(256), 0, stream>>>(x, Xh, Xl, N_NODES * FIN / 4);
    split_bf16<<<dim3(512), dim3(256), 0, stream>>>(W, Wh, Wl, DM * FIN / 4);
    gemm_mfma<<<dim3(8, 32), dim3(512), 0, stream>>>(Xh, Xl, Wh, Wl, bias, aL, aR,
                                                     C2, D2b, HbT);
    pack_mask<<<dim3(65536), dim3(256), 0, stream>>>(mask, mb);
    gat_attn<<<dim3(512), dim3(512), 0, stream>>>(HbT, C2, D2b, mb, out);
}